// Round 12
// baseline (194.792 us; speedup 1.0000x reference)
//
#include <hip/hip_runtime.h>
#include <hip/hip_bf16.h>
#include <math.h>

#define NEG_SLOPE 0.2f
#define LN_EPS 1e-5f

constexpr int B = 64, A = 256, L = 1024, D = 128;

typedef float f32x4 __attribute__((ext_vector_type(4)));
typedef float f32x16 __attribute__((ext_vector_type(16)));
typedef short bf16x8 __attribute__((ext_vector_type(8)));

__device__ __forceinline__ ushort f2bf(float x) {
    __hip_bfloat16 h = __float2bfloat16(x);
    return *reinterpret_cast<ushort*>(&h);
}
__device__ __forceinline__ float bf2f(ushort x) {
    unsigned u = ((unsigned)x) << 16;
    return __uint_as_float(u);
}
__device__ __forceinline__ void gl_lds16(const void* g, void* l) {
    __builtin_amdgcn_global_load_lds(
        (const __attribute__((address_space(1))) unsigned int*)g,
        (__attribute__((address_space(3))) unsigned int*)l, 16, 0, 0);
}
// rep-laundering: opaque zero so cross-rep load CSE is impossible (rule #17)
__device__ __forceinline__ unsigned opaque_zero() {
    unsigned z = 0;
    asm volatile("" : "+v"(z));
    return z;
}

// ---------------------------------------------------------------------------
// prep: u = W_mol@w_am, v = W_nb@w_aa, c0 = b_mol.w_am + b_al, c1 = b_nb.w_aa,
//       WB[e][d] = bf16(W_nb[d][e])
// ---------------------------------------------------------------------------
__global__ void prep_kernel(const float* __restrict__ Wmol, const float* __restrict__ bmol,
                            const float* __restrict__ wam, const float* __restrict__ bal,
                            const float* __restrict__ Wnb, const float* __restrict__ bnb,
                            const float* __restrict__ waa,
                            float* __restrict__ u, float* __restrict__ v,
                            float* __restrict__ c0, float* __restrict__ c1,
                            ushort* __restrict__ WB) {
    __shared__ float redU[2], redV[2], redC0[2], redC1[2];
    const int i = blockIdx.x, e = threadIdx.x;
    const int lane = e & 63, wv = e >> 6;
    float wnb_ie = Wnb[i * D + e];
    WB[e * D + i] = f2bf(wnb_ie);
    float pu = Wmol[i * D + e] * wam[e];
    float pv = wnb_ie * waa[e];
    float q0 = (i == 0) ? bmol[e] * wam[e] : 0.f;
    float q1 = (i == 0) ? bnb[e] * waa[e] : 0.f;
    #pragma unroll
    for (int o = 1; o < 64; o <<= 1) {
        pu += __shfl_xor(pu, o); pv += __shfl_xor(pv, o);
        q0 += __shfl_xor(q0, o); q1 += __shfl_xor(q1, o);
    }
    if (lane == 0) { redU[wv] = pu; redV[wv] = pv; redC0[wv] = q0; redC1[wv] = q1; }
    __syncthreads();
    if (e == 0) {
        u[i] = redU[0] + redU[1];
        v[i] = redV[0] + redV[1];
        if (i == 0) { c0[0] = redC0[0] + redC0[1] + bal[0];
                      c1[0] = redC1[0] + redC1[1]; }
    }
}

// ---------------------------------------------------------------------------
// smol: s_mol[b,a] = molf[b,a,:].u + c0
// ---------------------------------------------------------------------------
__global__ __launch_bounds__(256) void smol_kernel(
    const float* __restrict__ molf, const float* __restrict__ u,
    const float* __restrict__ c0p, float* __restrict__ smolG) {
    const int tid = threadIdx.x;
    const int r = tid >> 3, q = tid & 7;
    const int row = blockIdx.x * 32 + r;
    const float* xp = molf + (size_t)row * D + q * 16;
    float p = 0.f;
    #pragma unroll
    for (int k = 0; k < 4; ++k) {
        float4 xv = *(const float4*)&xp[k * 4];
        float4 uv = *(const float4*)&u[q * 16 + k * 4];
        p += xv.x * uv.x + xv.y * uv.y + xv.z * uv.z + xv.w * uv.w;
    }
    p += __shfl_xor(p, 1); p += __shfl_xor(p, 2); p += __shfl_xor(p, 4);
    if (q == 0) smolG[row] = p + c0p[0];
}

// ---------------------------------------------------------------------------
// trans x8 (DIAGNOSTIC REP): atom fp32 -> atomT bf16 [b][d][l] + masked s_atm
// ---------------------------------------------------------------------------
__global__ __launch_bounds__(256) void trans_kernel(
    const float* __restrict__ atom, const float* __restrict__ v,
    const float* __restrict__ c1p, const float* __restrict__ smask,
    ushort* __restrict__ atomT, float* __restrict__ sM) {
    __shared__ ushort Ls[64][132];
    const int tid = threadIdx.x;
    const int q = tid & 31, rg = tid >> 5;
    const int bidx = blockIdx.x;
    const int x = bidx & 7, j = bidx >> 3;
    const int b = x + 8 * (j & 7);
    const int l0 = (j >> 3) * 64;
    const float4 vq = *(const float4*)&v[q * 4];
    const float c1 = c1p[0];

    #pragma unroll 1
    for (int rep = 0; rep < 8; ++rep) {
        const unsigned z = opaque_zero();
        const float* atomz = atom + z;
        #pragma unroll
        for (int k = 0; k < 8; ++k) {
            const int l = rg * 8 + k;
            float4 xv = *(const float4*)&atomz[((size_t)b * L + l0 + l) * D + q * 4];
            float dot = xv.x * vq.x + xv.y * vq.y + xv.z * vq.z + xv.w * vq.w;
            dot += __shfl_xor(dot, 1);  dot += __shfl_xor(dot, 2);
            dot += __shfl_xor(dot, 4);  dot += __shfl_xor(dot, 8);
            dot += __shfl_xor(dot, 16);
            union { ushort us[4]; uint2 u2; } pk;
            pk.us[0] = f2bf(xv.x); pk.us[1] = f2bf(xv.y);
            pk.us[2] = f2bf(xv.z); pk.us[3] = f2bf(xv.w);
            *(uint2*)&Ls[l][q * 4] = pk.u2;
            if (q == 0) {
                float msk = smask[(size_t)b * L + l0 + l + z];
                sM[(size_t)b * L + l0 + l] = (msk > -0.5f) ? (dot + c1) : -1e30f;
            }
        }
        __syncthreads();
        {
            const int d = tid >> 1, h = tid & 1;
            #pragma unroll
            for (int jj = 0; jj < 4; ++jj) {
                alignas(16) ushort tmp[8];
                #pragma unroll
                for (int m = 0; m < 8; ++m) tmp[m] = Ls[h * 32 + jj * 8 + m][d];
                *(int4*)&atomT[((size_t)(b * 128 + d) << 10) + l0 + h * 32 + jj * 8] =
                    *(int4*)tmp;
            }
        }
        __syncthreads();
    }
}

// ---------------------------------------------------------------------------
// pv x8 (DIAGNOSTIC REP): stage 64 KB tile via gl_lds, one barrier, MFMA.
// ---------------------------------------------------------------------------
__global__ __launch_bounds__(256, 2) void pv_kernel(
    const ushort* __restrict__ atomT, const float* __restrict__ sM_g,
    const float* __restrict__ smolG,
    uint2* __restrict__ PP, float* __restrict__ psumP) {
    __shared__ __align__(16) ushort Ta[128][256];
    __shared__ ushort eT[256], fT[256];

    const int bid = blockIdx.x;
    const int x = bid & 7, j = bid >> 3;
    const int b = x + 8 * (j & 7);
    const int rest = j >> 3;
    const int lq = rest >> 1, ah = rest & 1;
    const int tid = threadIdx.x;
    const int w = tid >> 6, lane = tid & 63;
    const int al = lane & 31, hi = lane >> 5;

    #pragma unroll 1
    for (int rep = 0; rep < 8; ++rep) {
        const unsigned z = opaque_zero();
        const ushort* atomTb = atomT + (size_t)b * D * L + lq * 256 + z;

        #pragma unroll
        for (int q = 0; q < 16; ++q) {
            const int r0 = w * 32 + q * 2;
            const int r = r0 + hi;
            const ushort* g = atomTb + (size_t)r * L + ((al ^ (r & 15)) << 3);
            gl_lds16(g, (char*)&Ta[r0][0]);
        }
        {
            float s = sM_g[(size_t)b * L + lq * 256 + tid + z];
            eT[tid] = f2bf(__expf(s));
            fT[tid] = f2bf(__expf(NEG_SLOPE * s));
        }
        const int aG = ah * 128 + w * 32 + al;
        const float smv = smolG[(size_t)b * A + aG + z];
        const float ea = __expf(smv), fa = __expf(NEG_SLOPE * smv);
        __syncthreads();

        f32x16 acc[4] = {};
        float psum = 0.f;
        #pragma unroll 4
        for (int c = 0; c < 16; ++c) {
            const int lb = c * 16 + hi * 8;
            bf16x8 eb = *(const bf16x8*)&eT[lb];
            bf16x8 fb = *(const bf16x8*)&fT[lb];
            bf16x8 pf;
            #pragma unroll
            for (int jj = 0; jj < 8; ++jj) {
                float p_ = fmaxf(ea * bf2f((ushort)eb[jj]), fa * bf2f((ushort)fb[jj]));
                psum += p_;
                pf[jj] = (short)f2bf(p_);
            }
            const int ch = c * 2 + hi;
            #pragma unroll
            for (int dt = 0; dt < 4; ++dt) {
                const int row = dt * 32 + al;
                bf16x8 bf = *(const bf16x8*)((const char*)&Ta[0][0] + row * 512
                                             + ((ch ^ (row & 15)) << 4));
                acc[dt] = __builtin_amdgcn_mfma_f32_32x32x16_bf16(pf, bf, acc[dt], 0, 0, 0);
            }
        }

        psum += __shfl_xor(psum, 32);
        if (hi == 0) psumP[((size_t)b * 4 + lq) * A + aG] = psum;

        const size_t base0 = (((size_t)(b * 4 + lq) * 2 + ah) * 4 + w);
        #pragma unroll
        for (int dt = 0; dt < 4; ++dt) {
            #pragma unroll
            for (int rq = 0; rq < 4; ++rq) {
                union { ushort us[4]; uint2 u2; } pk;
                pk.us[0] = f2bf(acc[dt][rq * 4 + 0]);
                pk.us[1] = f2bf(acc[dt][rq * 4 + 1]);
                pk.us[2] = f2bf(acc[dt][rq * 4 + 2]);
                pk.us[3] = f2bf(acc[dt][rq * 4 + 3]);
                PP[((((base0 * 4 + dt) * 4 + rq) * 2 + hi) * 32) + al] = pk.u2;
            }
        }
        __syncthreads();
    }
}

// ---------------------------------------------------------------------------
// reduce x8 (DIAGNOSTIC REP): sum 4 lq partials -> TT -> ctx GEMM + LN -> out
// ---------------------------------------------------------------------------
__global__ __launch_bounds__(256) void reduce_kernel(
    const uint2* __restrict__ PP, const float* __restrict__ psumP,
    const float* __restrict__ amask, const ushort* __restrict__ WB,
    const float* __restrict__ bnb,
    const float* __restrict__ gamma, const float* __restrict__ beta,
    float* __restrict__ out) {
    __shared__ __align__(16) ushort TT[32 * 128];
    __shared__ float gbL[256];
    __shared__ float lnP[4][2][16][2];

    const int bid = blockIdx.x;
    const int x = bid & 7, j = bid >> 3;
    const int b = x + 8 * (j & 7);
    const int rest = j >> 3;
    const int ah = rest >> 2, at = rest & 3;
    const int tid = threadIdx.x;
    const int w = tid >> 6, lane = tid & 63;
    const int la = lane & 15, kg = lane >> 4;
    const int xo = la & 7;
    const int aG0 = ah * 128 + at * 32;

    if (tid < 32)      ((float4*)gbL)[tid] = ((const float4*)gamma)[tid];
    else if (tid < 64) ((float4*)gbL)[tid] = ((const float4*)beta)[tid - 32];

    #pragma unroll 1
    for (int rep = 0; rep < 8; ++rep) {
        const unsigned z = opaque_zero();
        {
            const int rq = tid >> 6, hi2 = (tid >> 5) & 1, al2 = tid & 31;
            float s4[4][4];
            #pragma unroll
            for (int dt = 0; dt < 4; ++dt)
                #pragma unroll
                for (int e = 0; e < 4; ++e) s4[dt][e] = 0.f;
            #pragma unroll
            for (int lq = 0; lq < 4; ++lq) {
                const size_t bb = (((size_t)(b * 4 + lq) * 2 + ah) * 4 + at);
                #pragma unroll
                for (int dt = 0; dt < 4; ++dt) {
                    uint2 v = PP[((((bb * 4 + dt) * 4 + rq) * 2 + hi2) * 32) + al2 + z];
                    s4[dt][0] += bf2f((ushort)(v.x & 0xffff));
                    s4[dt][1] += bf2f((ushort)(v.x >> 16));
                    s4[dt][2] += bf2f((ushort)(v.y & 0xffff));
                    s4[dt][3] += bf2f((ushort)(v.y >> 16));
                }
            }
            #pragma unroll
            for (int dt = 0; dt < 4; ++dt) {
                const int d = dt * 32 + al2;
                const int cc = d >> 3;
                #pragma unroll
                for (int e = 0; e < 4; ++e) {
                    const int arow = e + 8 * rq + 4 * hi2;
                    *(ushort*)((char*)TT + arow * 256 + ((cc ^ (arow & 7)) << 4)
                               + (d & 7) * 2) = f2bf(s4[dt][e]);
                }
            }
        }

        bf16x8 wb0[4], wb1[4];
        {
            const ushort* wr0 = WB + (size_t)((2 * w) * 16 + la) * D + kg * 8 + z;
            const ushort* wr1 = WB + (size_t)((2 * w + 1) * 16 + la) * D + kg * 8 + z;
            #pragma unroll
            for (int ks = 0; ks < 4; ++ks) {
                wb0[ks] = *(const bf16x8*)&wr0[ks * 32];
                wb1[ks] = *(const bf16x8*)&wr1[ks * 32];
            }
        }
        float4 bias0 = *(const float4*)&bnb[w * 32 + kg * 4];
        float4 bias1 = *(const float4*)&bnb[w * 32 + 16 + kg * 4];
        const float amA = amask[(size_t)b * A + aG0 + la + z];
        const float amB = amask[(size_t)b * A + aG0 + 16 + la + z];
        float psA = 0.f, psB = 0.f;
        #pragma unroll
        for (int lq = 0; lq < 4; ++lq) {
            psA += psumP[((size_t)b * 4 + lq) * A + aG0 + la + z];
            psB += psumP[((size_t)b * 4 + lq) * A + aG0 + 16 + la + z];
        }
        __syncthreads();

        const char* TTc = (const char*)TT;
#define LDT(ROW_, KS_) (*(const bf16x8*)(TTc + (ROW_) * 256 + \
                         ((((KS_) * 4 + kg) ^ xo) << 4)))
        f32x4 cA0 = {}, cA1 = {}, cB0 = {}, cB1 = {};
        #pragma unroll
        for (int ks = 0; ks < 4; ++ks) {
            bf16x8 tA = LDT(la, ks);
            bf16x8 tB = LDT(la + 16, ks);
            cA0 = __builtin_amdgcn_mfma_f32_16x16x32_bf16(wb0[ks], tA, cA0, 0, 0, 0);
            cA1 = __builtin_amdgcn_mfma_f32_16x16x32_bf16(wb1[ks], tA, cA1, 0, 0, 0);
            cB0 = __builtin_amdgcn_mfma_f32_16x16x32_bf16(wb0[ks], tB, cB0, 0, 0, 0);
            cB1 = __builtin_amdgcn_mfma_f32_16x16x32_bf16(wb1[ks], tB, cB1, 0, 0, 0);
        }
#undef LDT

        const float scA = amA / psA, scB = amB / psB;
        float xA[8], xB[8];
        float s1A = 0.f, s2A = 0.f, s1B = 0.f, s2B = 0.f;
        const float* bp0 = (const float*)&bias0;
        const float* bp1 = (const float*)&bias1;
        #pragma unroll
        for (int r = 0; r < 4; ++r) {
            xA[r]     = cA0[r] * scA + amA * bp0[r];
            xA[4 + r] = cA1[r] * scA + amA * bp1[r];
            xB[r]     = cB0[r] * scB + amB * bp0[r];
            xB[4 + r] = cB1[r] * scB + amB * bp1[r];
            s1A += xA[r] + xA[4 + r]; s2A += xA[r] * xA[r] + xA[4 + r] * xA[4 + r];
            s1B += xB[r] + xB[4 + r]; s2B += xB[r] * xB[r] + xB[4 + r] * xB[4 + r];
        }
        s1A += __shfl_xor(s1A, 16); s1A += __shfl_xor(s1A, 32);
        s2A += __shfl_xor(s2A, 16); s2A += __shfl_xor(s2A, 32);
        s1B += __shfl_xor(s1B, 16); s1B += __shfl_xor(s1B, 32);
        s2B += __shfl_xor(s2B, 16); s2B += __shfl_xor(s2B, 32);
        if (lane < 16) {
            lnP[w][0][la][0] = s1A; lnP[w][0][la][1] = s2A;
            lnP[w][1][la][0] = s1B; lnP[w][1][la][1] = s2B;
        }
        __syncthreads();
        const float S1A = lnP[0][0][la][0] + lnP[1][0][la][0] + lnP[2][0][la][0] + lnP[3][0][la][0];
        const float S2A = lnP[0][0][la][1] + lnP[1][0][la][1] + lnP[2][0][la][1] + lnP[3][0][la][1];
        const float S1B = lnP[0][1][la][0] + lnP[1][1][la][0] + lnP[2][1][la][0] + lnP[3][1][la][0];
        const float S2B = lnP[0][1][la][1] + lnP[1][1][la][1] + lnP[2][1][la][1] + lnP[3][1][la][1];
        const float muA = S1A * (1.f / 128.f);
        const float rsA = rsqrtf(S2A * (1.f / 128.f) - muA * muA + LN_EPS);
        const float muB = S1B * (1.f / 128.f);
        const float rsB = rsqrtf(S2B * (1.f / 128.f) - muB * muB + LN_EPS);
        const size_t oA = ((size_t)b * A + aG0 + la) * D;
        const size_t oB = ((size_t)b * A + aG0 + 16 + la) * D;
        #pragma unroll
        for (int t = 0; t < 2; ++t) {
            const int e0 = w * 32 + t * 16 + kg * 4;
            float4 g4 = *(float4*)&gbL[e0];
            float4 b4 = *(float4*)&gbL[128 + e0];
            float4 ovA, ovB;
            const float* xpA = &xA[t * 4];
            const float* xpB = &xB[t * 4];
            ((float*)&ovA)[0] = (xpA[0] - muA) * rsA * g4.x + b4.x;
            ((float*)&ovA)[1] = (xpA[1] - muA) * rsA * g4.y + b4.y;
            ((float*)&ovA)[2] = (xpA[2] - muA) * rsA * g4.z + b4.z;
            ((float*)&ovA)[3] = (xpA[3] - muA) * rsA * g4.w + b4.w;
            ((float*)&ovB)[0] = (xpB[0] - muB) * rsB * g4.x + b4.x;
            ((float*)&ovB)[1] = (xpB[1] - muB) * rsB * g4.y + b4.y;
            ((float*)&ovB)[2] = (xpB[2] - muB) * rsB * g4.z + b4.z;
            ((float*)&ovB)[3] = (xpB[3] - muB) * rsB * g4.w + b4.w;
            *(float4*)&out[oA + e0] = ovA;
            *(float4*)&out[oB + e0] = ovB;
        }
        __syncthreads();
    }
}

// ---------------------------------------------------------------------------
extern "C" void kernel_launch(void* const* d_in, const int* in_sizes, int n_in,
                              void* d_out, int out_size, void* d_ws, size_t ws_size,
                              hipStream_t stream) {
    const float* molf  = (const float*)d_in[0];
    const float* atomf = (const float*)d_in[1];
    const float* amask = (const float*)d_in[2];
    const float* smask = (const float*)d_in[3];
    const float* W_mol = (const float*)d_in[4];
    const float* b_mol = (const float*)d_in[5];
    const float* W_nb  = (const float*)d_in[6];
    const float* b_nb  = (const float*)d_in[7];
    const float* w_am  = (const float*)d_in[8];
    const float* w_aa  = (const float*)d_in[9];
    const float* b_al  = (const float*)d_in[10];
    const float* gamma = (const float*)d_in[11];
    const float* beta  = (const float*)d_in[12];
    float* out = (float*)d_out;

    ushort* atomT = (ushort*)d_ws;
    uint2* PP     = (uint2*)(atomT + (size_t)B * D * L);
    float* sM     = (float*)(PP + (size_t)B * 4 * A * D / 4);
    float* smolG  = sM + (size_t)B * L;
    float* psumP  = smolG + (size_t)B * A;
    float* u_ws   = psumP + (size_t)B * 4 * A;
    float* v_ws   = u_ws + D;
    float* c0_ws  = v_ws + D;
    float* c1_ws  = c0_ws + 1;
    ushort* WB    = (ushort*)(c1_ws + 1);

    prep_kernel<<<128, 128, 0, stream>>>(W_mol, b_mol, w_am, b_al, W_nb, b_nb,
                                         w_aa, u_ws, v_ws, c0_ws, c1_ws, WB);
    smol_kernel<<<(B * A) / 32, 256, 0, stream>>>(molf, u_ws, c0_ws, smolG);
    trans_kernel<<<(B * L) / 64, 256, 0, stream>>>(atomf, v_ws, c1_ws, smask,
                                                   atomT, sM);
    pv_kernel<<<512, 256, 0, stream>>>(atomT, sM, smolG, PP, psumP);
    reduce_kernel<<<512, 256, 0, stream>>>(PP, psumP, amask, WB, b_nb,
                                           gamma, beta, out);
}

// Round 13
// 122.713 us; speedup vs baseline: 1.5874x; 1.5874x over previous
//
#include <hip/hip_runtime.h>
#include <hip/hip_bf16.h>
#include <math.h>

#define NEG_SLOPE 0.2f
#define LN_EPS 1e-5f

constexpr int B = 64, A = 256, L = 1024, D = 128;

typedef float f32x4 __attribute__((ext_vector_type(4)));
typedef float f32x16 __attribute__((ext_vector_type(16)));
typedef short bf16x8 __attribute__((ext_vector_type(8)));

__device__ __forceinline__ ushort f2bf(float x) {
    __hip_bfloat16 h = __float2bfloat16(x);
    return *reinterpret_cast<ushort*>(&h);
}
__device__ __forceinline__ float bf2f(ushort x) {
    unsigned u = ((unsigned)x) << 16;
    return __uint_as_float(u);
}
__device__ __forceinline__ void gl_lds16(const void* g, void* l) {
    __builtin_amdgcn_global_load_lds(
        (const __attribute__((address_space(1))) unsigned int*)g,
        (__attribute__((address_space(3))) unsigned int*)l, 16, 0, 0);
}

// ---------------------------------------------------------------------------
// K2 "pre": concatenated grid of 8 aux + 512 smol + 1024 trans blocks.
//   aux   : WB[e][d] = bf16(Wnb[d][e]); zero reduction counters.
//   smol  : u = Wmol@wam inline (L2-hot), s_mol[b,a] = molf.u + c0.
//   trans : v = Wnb@waa inline, atom fp32 -> atomT bf16 [b][d][l] + masked sM.
// ---------------------------------------------------------------------------
__global__ __launch_bounds__(256) void pre_kernel(
    const float* __restrict__ molf, const float* __restrict__ atom,
    const float* __restrict__ smask,
    const float* __restrict__ Wmol, const float* __restrict__ bmol,
    const float* __restrict__ wam, const float* __restrict__ bal,
    const float* __restrict__ Wnb, const float* __restrict__ bnb,
    const float* __restrict__ waa,
    float* __restrict__ smolG, ushort* __restrict__ atomT,
    float* __restrict__ sM, ushort* __restrict__ WB,
    unsigned* __restrict__ cnt) {
    const int bid = blockIdx.x;
    const int tid = threadIdx.x;
    __shared__ __align__(16) ushort Ls[64][132];   // trans bounce
    __shared__ __align__(16) float wvL[128];       // u or v
    __shared__ float ccL[4];

    if (bid < 8) {
        // ---- aux: WB conversion + counter zero
        const int e = bid * 16 + (tid >> 4);
        const int d0 = (tid & 15) * 8;
        union { ushort us[8]; int4 v; } pk;
        #pragma unroll
        for (int k = 0; k < 8; ++k) pk.us[k] = f2bf(Wnb[(size_t)(d0 + k) * D + e]);
        *(int4*)&WB[(size_t)e * D + d0] = pk.v;
        if (bid == 0 && tid < 128) cnt[tid] = 0u;
        return;
    }

    if (bid < 520) {
        // ---- smol chunk c: rows [c*32, c*32+32)
        const int c = bid - 8;
        {   // u inline: i = tid>>1 over e-half h
            const int i = tid >> 1, h = tid & 1;
            const float* wrow = Wmol + (size_t)i * D + h * 64;
            const float* wa = wam + h * 64;
            float s = 0.f;
            #pragma unroll
            for (int k = 0; k < 16; ++k) {
                float4 a = *(const float4*)&wrow[k * 4];
                float4 b2 = *(const float4*)&wa[k * 4];
                s += a.x * b2.x + a.y * b2.y + a.z * b2.z + a.w * b2.w;
            }
            s += __shfl_xor(s, 1);
            if (h == 0) wvL[i] = s;
        }
        {   // c0 partial
            float t = (tid < 128) ? bmol[tid] * wam[tid] : 0.f;
            #pragma unroll
            for (int o = 1; o < 64; o <<= 1) t += __shfl_xor(t, o);
            if ((tid & 63) == 0) ccL[tid >> 6] = t;
        }
        __syncthreads();
        const float c0 = ccL[0] + ccL[1] + ccL[2] + ccL[3] + bal[0];
        const int r = tid >> 3, q = tid & 7;
        const int row = c * 32 + r;
        const float* xp = molf + (size_t)row * D + q * 16;
        float p = 0.f;
        #pragma unroll
        for (int k = 0; k < 4; ++k) {
            float4 xv = *(const float4*)&xp[k * 4];
            float4 uv = *(const float4*)&wvL[q * 16 + k * 4];
            p += xv.x * uv.x + xv.y * uv.y + xv.z * uv.z + xv.w * uv.w;
        }
        p += __shfl_xor(p, 1); p += __shfl_xor(p, 2); p += __shfl_xor(p, 4);
        if (q == 0) smolG[row] = p + c0;
        return;
    }

    // ---- trans chunk cc (XCD mapping preserved: 520 % 8 == 0)
    const int cc = bid - 520;
    const int x = cc & 7, j = cc >> 3;
    const int b = x + 8 * (j & 7);
    const int l0 = (j >> 3) * 64;
    {   // v inline
        const int i = tid >> 1, h = tid & 1;
        const float* wrow = Wnb + (size_t)i * D + h * 64;
        const float* wa = waa + h * 64;
        float s = 0.f;
        #pragma unroll
        for (int k = 0; k < 16; ++k) {
            float4 a = *(const float4*)&wrow[k * 4];
            float4 b2 = *(const float4*)&wa[k * 4];
            s += a.x * b2.x + a.y * b2.y + a.z * b2.z + a.w * b2.w;
        }
        s += __shfl_xor(s, 1);
        if (h == 0) wvL[i] = s;
    }
    {   // c1 partial
        float t = (tid < 128) ? bnb[tid] * waa[tid] : 0.f;
        #pragma unroll
        for (int o = 1; o < 64; o <<= 1) t += __shfl_xor(t, o);
        if ((tid & 63) == 0) ccL[tid >> 6] = t;
    }
    __syncthreads();
    const float c1 = ccL[0] + ccL[1] + ccL[2] + ccL[3];
    const int q = tid & 31, rg = tid >> 5;
    const float4 vq = *(const float4*)&wvL[q * 4];

    #pragma unroll
    for (int k = 0; k < 8; ++k) {
        const int l = rg * 8 + k;
        float4 xv = *(const float4*)&atom[((size_t)b * L + l0 + l) * D + q * 4];
        float dot = xv.x * vq.x + xv.y * vq.y + xv.z * vq.z + xv.w * vq.w;
        dot += __shfl_xor(dot, 1);  dot += __shfl_xor(dot, 2);
        dot += __shfl_xor(dot, 4);  dot += __shfl_xor(dot, 8);
        dot += __shfl_xor(dot, 16);
        union { ushort us[4]; uint2 u2; } pk;
        pk.us[0] = f2bf(xv.x); pk.us[1] = f2bf(xv.y);
        pk.us[2] = f2bf(xv.z); pk.us[3] = f2bf(xv.w);
        *(uint2*)&Ls[l][q * 4] = pk.u2;
        if (q == 0) {
            float msk = smask[(size_t)b * L + l0 + l];
            sM[(size_t)b * L + l0 + l] = (msk > -0.5f) ? (dot + c1) : -1e30f;
        }
    }
    __syncthreads();
    {
        const int d = tid >> 1, h = tid & 1;
        #pragma unroll
        for (int jj = 0; jj < 4; ++jj) {
            alignas(16) ushort tmp[8];
            #pragma unroll
            for (int m = 0; m < 8; ++m) tmp[m] = Ls[h * 32 + jj * 8 + m][d];
            *(int4*)&atomT[((size_t)(b * 128 + d) << 10) + l0 + h * 32 + jj * 8] =
                *(int4*)tmp;
        }
    }
}

// ---------------------------------------------------------------------------
// K3 "pv_reduce": 512 blocks (b, lq, ah). pv body (R11-verified) writes
// partials; the LAST block of each (b,ah) group (device-scope atomic counter)
// performs the 4 at-chunk reductions (R11-verified body, TT overlaid on Ta).
// ---------------------------------------------------------------------------
__global__ __launch_bounds__(256, 2) void pv_reduce_kernel(
    const ushort* __restrict__ atomT, const float* __restrict__ sM_g,
    const float* __restrict__ smolG,
    uint2* __restrict__ PP, float* __restrict__ psumP,
    unsigned* __restrict__ cnt,
    const float* __restrict__ amask, const ushort* __restrict__ WB,
    const float* __restrict__ bnb,
    const float* __restrict__ gamma, const float* __restrict__ beta,
    float* __restrict__ out) {
    __shared__ __align__(16) ushort Ta[128][256];      // 64 KB (TT overlays)
    __shared__ ushort eT[256], fT[256];
    __shared__ float gbL[256];
    __shared__ float lnP[4][2][16][2];
    __shared__ unsigned doneS;

    const int bid = blockIdx.x;
    const int x = bid & 7, j = bid >> 3;
    const int b = x + 8 * (j & 7);
    const int rest = j >> 3;
    const int lq = rest >> 1, ah = rest & 1;
    const int tid = threadIdx.x;
    const int w = tid >> 6, lane = tid & 63;
    const int al = lane & 31, hi = lane >> 5;
    const int la = lane & 15, kg = lane >> 4;
    const int xo = la & 7;

    const ushort* atomTb = atomT + (size_t)b * D * L + lq * 256;

    #pragma unroll
    for (int q = 0; q < 16; ++q) {
        const int r0 = w * 32 + q * 2;
        const int r = r0 + hi;
        const ushort* g = atomTb + (size_t)r * L + ((al ^ (r & 15)) << 3);
        gl_lds16(g, (char*)&Ta[r0][0]);
    }
    {
        float s = sM_g[(size_t)b * L + lq * 256 + tid];
        eT[tid] = f2bf(__expf(s));
        fT[tid] = f2bf(__expf(NEG_SLOPE * s));
    }
    const int aG = ah * 128 + w * 32 + al;
    const float smv = smolG[(size_t)b * A + aG];
    const float ea = __expf(smv), fa = __expf(NEG_SLOPE * smv);
    __syncthreads();

    f32x16 acc[4] = {};
    float psum = 0.f;
    #pragma unroll 4
    for (int c = 0; c < 16; ++c) {
        const int lb = c * 16 + hi * 8;
        bf16x8 eb = *(const bf16x8*)&eT[lb];
        bf16x8 fb = *(const bf16x8*)&fT[lb];
        bf16x8 pf;
        #pragma unroll
        for (int jj = 0; jj < 8; ++jj) {
            float p_ = fmaxf(ea * bf2f((ushort)eb[jj]), fa * bf2f((ushort)fb[jj]));
            psum += p_;
            pf[jj] = (short)f2bf(p_);
        }
        const int ch = c * 2 + hi;
        #pragma unroll
        for (int dt = 0; dt < 4; ++dt) {
            const int row = dt * 32 + al;
            bf16x8 bf = *(const bf16x8*)((const char*)&Ta[0][0] + row * 512
                                         + ((ch ^ (row & 15)) << 4));
            acc[dt] = __builtin_amdgcn_mfma_f32_32x32x16_bf16(pf, bf, acc[dt], 0, 0, 0);
        }
    }

    psum += __shfl_xor(psum, 32);
    if (hi == 0) psumP[((size_t)b * 4 + lq) * A + aG] = psum;

    const size_t base0 = (((size_t)(b * 4 + lq) * 2 + ah) * 4 + w);
    #pragma unroll
    for (int dt = 0; dt < 4; ++dt) {
        #pragma unroll
        for (int rq = 0; rq < 4; ++rq) {
            union { ushort us[4]; uint2 u2; } pk;
            pk.us[0] = f2bf(acc[dt][rq * 4 + 0]);
            pk.us[1] = f2bf(acc[dt][rq * 4 + 1]);
            pk.us[2] = f2bf(acc[dt][rq * 4 + 2]);
            pk.us[3] = f2bf(acc[dt][rq * 4 + 3]);
            PP[((((base0 * 4 + dt) * 4 + rq) * 2 + hi) * 32) + al] = pk.u2;
        }
    }

    // ---- tail: last block of (b,ah) performs the reduction
    __threadfence();                       // release partials (device scope)
    if (tid == 0) doneS = atomicAdd(&cnt[b * 2 + ah], 1u);
    __syncthreads();
    if (doneS != 3) return;
    __threadfence();                       // acquire others' partials

    if (tid < 32)      ((float4*)gbL)[tid] = ((const float4*)gamma)[tid];
    else if (tid < 64) ((float4*)gbL)[tid] = ((const float4*)beta)[tid - 32];

    // at-independent GEMM operands
    bf16x8 wb0[4], wb1[4];
    {
        const ushort* wr0 = WB + (size_t)((2 * w) * 16 + la) * D + kg * 8;
        const ushort* wr1 = WB + (size_t)((2 * w + 1) * 16 + la) * D + kg * 8;
        #pragma unroll
        for (int ks = 0; ks < 4; ++ks) {
            wb0[ks] = *(const bf16x8*)&wr0[ks * 32];
            wb1[ks] = *(const bf16x8*)&wr1[ks * 32];
        }
    }
    float4 bias0 = *(const float4*)&bnb[w * 32 + kg * 4];
    float4 bias1 = *(const float4*)&bnb[w * 32 + 16 + kg * 4];
    ushort* TT = &Ta[0][0];

    for (int at = 0; at < 4; ++at) {
        __syncthreads();   // TT/lnP free from previous iteration
        const int aG0 = ah * 128 + at * 32;
        {
            const int rq = tid >> 6, hi2 = (tid >> 5) & 1, al2 = tid & 31;
            float s4[4][4];
            #pragma unroll
            for (int dt = 0; dt < 4; ++dt)
                #pragma unroll
                for (int e = 0; e < 4; ++e) s4[dt][e] = 0.f;
            #pragma unroll
            for (int lq2 = 0; lq2 < 4; ++lq2) {
                const size_t bb = (((size_t)(b * 4 + lq2) * 2 + ah) * 4 + at);
                #pragma unroll
                for (int dt = 0; dt < 4; ++dt) {
                    uint2 v = PP[((((bb * 4 + dt) * 4 + rq) * 2 + hi2) * 32) + al2];
                    s4[dt][0] += bf2f((ushort)(v.x & 0xffff));
                    s4[dt][1] += bf2f((ushort)(v.x >> 16));
                    s4[dt][2] += bf2f((ushort)(v.y & 0xffff));
                    s4[dt][3] += bf2f((ushort)(v.y >> 16));
                }
            }
            #pragma unroll
            for (int dt = 0; dt < 4; ++dt) {
                const int d = dt * 32 + al2;
                const int ccd = d >> 3;
                #pragma unroll
                for (int e = 0; e < 4; ++e) {
                    const int arow = e + 8 * rq + 4 * hi2;
                    *(ushort*)((char*)TT + arow * 256 + ((ccd ^ (arow & 7)) << 4)
                               + (d & 7) * 2) = f2bf(s4[dt][e]);
                }
            }
        }
        const float amA = amask[(size_t)b * A + aG0 + la];
        const float amB = amask[(size_t)b * A + aG0 + 16 + la];
        float psA = 0.f, psB = 0.f;
        #pragma unroll
        for (int lq2 = 0; lq2 < 4; ++lq2) {
            psA += psumP[((size_t)b * 4 + lq2) * A + aG0 + la];
            psB += psumP[((size_t)b * 4 + lq2) * A + aG0 + 16 + la];
        }
        __syncthreads();

        const char* TTc = (const char*)TT;
#define LDT(ROW_, KS_) (*(const bf16x8*)(TTc + (ROW_) * 256 + \
                         ((((KS_) * 4 + kg) ^ xo) << 4)))
        f32x4 cA0 = {}, cA1 = {}, cB0 = {}, cB1 = {};
        #pragma unroll
        for (int ks = 0; ks < 4; ++ks) {
            bf16x8 tA = LDT(la, ks);
            bf16x8 tB = LDT(la + 16, ks);
            cA0 = __builtin_amdgcn_mfma_f32_16x16x32_bf16(wb0[ks], tA, cA0, 0, 0, 0);
            cA1 = __builtin_amdgcn_mfma_f32_16x16x32_bf16(wb1[ks], tA, cA1, 0, 0, 0);
            cB0 = __builtin_amdgcn_mfma_f32_16x16x32_bf16(wb0[ks], tB, cB0, 0, 0, 0);
            cB1 = __builtin_amdgcn_mfma_f32_16x16x32_bf16(wb1[ks], tB, cB1, 0, 0, 0);
        }
#undef LDT

        const float scA = amA / psA, scB = amB / psB;
        float xA[8], xB[8];
        float s1A = 0.f, s2A = 0.f, s1B = 0.f, s2B = 0.f;
        const float* bp0 = (const float*)&bias0;
        const float* bp1 = (const float*)&bias1;
        #pragma unroll
        for (int r = 0; r < 4; ++r) {
            xA[r]     = cA0[r] * scA + amA * bp0[r];
            xA[4 + r] = cA1[r] * scA + amA * bp1[r];
            xB[r]     = cB0[r] * scB + amB * bp0[r];
            xB[4 + r] = cB1[r] * scB + amB * bp1[r];
            s1A += xA[r] + xA[4 + r]; s2A += xA[r] * xA[r] + xA[4 + r] * xA[4 + r];
            s1B += xB[r] + xB[4 + r]; s2B += xB[r] * xB[r] + xB[4 + r] * xB[4 + r];
        }
        s1A += __shfl_xor(s1A, 16); s1A += __shfl_xor(s1A, 32);
        s2A += __shfl_xor(s2A, 16); s2A += __shfl_xor(s2A, 32);
        s1B += __shfl_xor(s1B, 16); s1B += __shfl_xor(s1B, 32);
        s2B += __shfl_xor(s2B, 16); s2B += __shfl_xor(s2B, 32);
        if (lane < 16) {
            lnP[w][0][la][0] = s1A; lnP[w][0][la][1] = s2A;
            lnP[w][1][la][0] = s1B; lnP[w][1][la][1] = s2B;
        }
        __syncthreads();
        const float S1A = lnP[0][0][la][0] + lnP[1][0][la][0] + lnP[2][0][la][0] + lnP[3][0][la][0];
        const float S2A = lnP[0][0][la][1] + lnP[1][0][la][1] + lnP[2][0][la][1] + lnP[3][0][la][1];
        const float S1B = lnP[0][1][la][0] + lnP[1][1][la][0] + lnP[2][1][la][0] + lnP[3][1][la][0];
        const float S2B = lnP[0][1][la][1] + lnP[1][1][la][1] + lnP[2][1][la][1] + lnP[3][1][la][1];
        const float muA = S1A * (1.f / 128.f);
        const float rsA = rsqrtf(S2A * (1.f / 128.f) - muA * muA + LN_EPS);
        const float muB = S1B * (1.f / 128.f);
        const float rsB = rsqrtf(S2B * (1.f / 128.f) - muB * muB + LN_EPS);
        const size_t oA = ((size_t)b * A + aG0 + la) * D;
        const size_t oB = ((size_t)b * A + aG0 + 16 + la) * D;
        #pragma unroll
        for (int t = 0; t < 2; ++t) {
            const int e0 = w * 32 + t * 16 + kg * 4;
            float4 g4 = *(float4*)&gbL[e0];
            float4 b4 = *(float4*)&gbL[128 + e0];
            float4 ovA, ovB;
            const float* xpA = &xA[t * 4];
            const float* xpB = &xB[t * 4];
            ((float*)&ovA)[0] = (xpA[0] - muA) * rsA * g4.x + b4.x;
            ((float*)&ovA)[1] = (xpA[1] - muA) * rsA * g4.y + b4.y;
            ((float*)&ovA)[2] = (xpA[2] - muA) * rsA * g4.z + b4.z;
            ((float*)&ovA)[3] = (xpA[3] - muA) * rsA * g4.w + b4.w;
            ((float*)&ovB)[0] = (xpB[0] - muB) * rsB * g4.x + b4.x;
            ((float*)&ovB)[1] = (xpB[1] - muB) * rsB * g4.y + b4.y;
            ((float*)&ovB)[2] = (xpB[2] - muB) * rsB * g4.z + b4.z;
            ((float*)&ovB)[3] = (xpB[3] - muB) * rsB * g4.w + b4.w;
            *(float4*)&out[oA + e0] = ovA;
            *(float4*)&out[oB + e0] = ovB;
        }
    }
}

// ---------------------------------------------------------------------------
extern "C" void kernel_launch(void* const* d_in, const int* in_sizes, int n_in,
                              void* d_out, int out_size, void* d_ws, size_t ws_size,
                              hipStream_t stream) {
    const float* molf  = (const float*)d_in[0];
    const float* atomf = (const float*)d_in[1];
    const float* amask = (const float*)d_in[2];
    const float* smask = (const float*)d_in[3];
    const float* W_mol = (const float*)d_in[4];
    const float* b_mol = (const float*)d_in[5];
    const float* W_nb  = (const float*)d_in[6];
    const float* b_nb  = (const float*)d_in[7];
    const float* w_am  = (const float*)d_in[8];
    const float* w_aa  = (const float*)d_in[9];
    const float* b_al  = (const float*)d_in[10];
    const float* gamma = (const float*)d_in[11];
    const float* beta  = (const float*)d_in[12];
    float* out = (float*)d_out;

    // ws: atomT bf16 [B*D*L] | PP uint2 [B*4*A*D/4] | sM [B*L] | smol [B*A]
    //     | psumP [B*4*A] | WB bf16 [D*D] | cnt u32 [128]
    ushort* atomT = (ushort*)d_ws;
    uint2* PP     = (uint2*)(atomT + (size_t)B * D * L);
    float* sM     = (float*)(PP + (size_t)B * 4 * A * D / 4);
    float* smolG  = sM + (size_t)B * L;
    float* psumP  = smolG + (size_t)B * A;
    ushort* WB    = (ushort*)(psumP + (size_t)B * 4 * A);
    unsigned* cnt = (unsigned*)(WB + D * D);

    pre_kernel<<<8 + 512 + 1024, 256, 0, stream>>>(
        molf, atomf, smask, W_mol, b_mol, w_am, b_al, W_nb, b_nb, w_aa,
        smolG, atomT, sM, WB, cnt);
    pv_reduce_kernel<<<512, 256, 0, stream>>>(
        atomT, sM, smolG, PP, psumP, cnt, amask, WB, b_nb, gamma, beta, out);
}

// Round 14
// 54.577 us; speedup vs baseline: 3.5691x; 2.2484x over previous
//
#include <hip/hip_runtime.h>
#include <hip/hip_bf16.h>
#include <math.h>

#define NEG_SLOPE 0.2f
#define LN_EPS 1e-5f

constexpr int B = 64, A = 256, L = 1024, D = 128;

typedef float f32x4 __attribute__((ext_vector_type(4)));
typedef float f32x16 __attribute__((ext_vector_type(16)));
typedef short bf16x8 __attribute__((ext_vector_type(8)));

__device__ __forceinline__ ushort f2bf(float x) {
    __hip_bfloat16 h = __float2bfloat16(x);
    return *reinterpret_cast<ushort*>(&h);
}
__device__ __forceinline__ float bf2f(ushort x) {
    unsigned u = ((unsigned)x) << 16;
    return __uint_as_float(u);
}
__device__ __forceinline__ void gl_lds16(const void* g, void* l) {
    __builtin_amdgcn_global_load_lds(
        (const __attribute__((address_space(1))) unsigned int*)g,
        (__attribute__((address_space(3))) unsigned int*)l, 16, 0, 0);
}

// ---------------------------------------------------------------------------
// K1 "pre": concatenated grid of 8 aux + 512 smol + 1024 trans blocks.
//   aux   : WB[e][d] = bf16(Wnb[d][e]).
//   smol  : u = Wmol@wam inline (L2-hot), s_mol[b,a] = molf.u + c0.
//   trans : v = Wnb@waa inline, atom fp32 -> atomT bf16 [b][d][l] + masked sM.
// (Body verified in R13.)
// ---------------------------------------------------------------------------
__global__ __launch_bounds__(256) void pre_kernel(
    const float* __restrict__ molf, const float* __restrict__ atom,
    const float* __restrict__ smask,
    const float* __restrict__ Wmol, const float* __restrict__ bmol,
    const float* __restrict__ wam, const float* __restrict__ bal,
    const float* __restrict__ Wnb, const float* __restrict__ bnb,
    const float* __restrict__ waa,
    float* __restrict__ smolG, ushort* __restrict__ atomT,
    float* __restrict__ sM, ushort* __restrict__ WB) {
    const int bid = blockIdx.x;
    const int tid = threadIdx.x;
    __shared__ __align__(16) ushort Ls[64][132];   // trans bounce
    __shared__ __align__(16) float wvL[128];       // u or v
    __shared__ float ccL[4];

    if (bid < 8) {
        const int e = bid * 16 + (tid >> 4);
        const int d0 = (tid & 15) * 8;
        union { ushort us[8]; int4 v; } pk;
        #pragma unroll
        for (int k = 0; k < 8; ++k) pk.us[k] = f2bf(Wnb[(size_t)(d0 + k) * D + e]);
        *(int4*)&WB[(size_t)e * D + d0] = pk.v;
        return;
    }

    if (bid < 520) {
        // ---- smol chunk c: rows [c*32, c*32+32)
        const int c = bid - 8;
        {
            const int i = tid >> 1, h = tid & 1;
            const float* wrow = Wmol + (size_t)i * D + h * 64;
            const float* wa = wam + h * 64;
            float s = 0.f;
            #pragma unroll
            for (int k = 0; k < 16; ++k) {
                float4 a = *(const float4*)&wrow[k * 4];
                float4 b2 = *(const float4*)&wa[k * 4];
                s += a.x * b2.x + a.y * b2.y + a.z * b2.z + a.w * b2.w;
            }
            s += __shfl_xor(s, 1);
            if (h == 0) wvL[i] = s;
        }
        {
            float t = (tid < 128) ? bmol[tid] * wam[tid] : 0.f;
            #pragma unroll
            for (int o = 1; o < 64; o <<= 1) t += __shfl_xor(t, o);
            if ((tid & 63) == 0) ccL[tid >> 6] = t;
        }
        __syncthreads();
        const float c0 = ccL[0] + ccL[1] + ccL[2] + ccL[3] + bal[0];
        const int r = tid >> 3, q = tid & 7;
        const int row = c * 32 + r;
        const float* xp = molf + (size_t)row * D + q * 16;
        float p = 0.f;
        #pragma unroll
        for (int k = 0; k < 4; ++k) {
            float4 xv = *(const float4*)&xp[k * 4];
            float4 uv = *(const float4*)&wvL[q * 16 + k * 4];
            p += xv.x * uv.x + xv.y * uv.y + xv.z * uv.z + xv.w * uv.w;
        }
        p += __shfl_xor(p, 1); p += __shfl_xor(p, 2); p += __shfl_xor(p, 4);
        if (q == 0) smolG[row] = p + c0;
        return;
    }

    // ---- trans chunk cc (XCD mapping preserved: 520 % 8 == 0)
    const int cc = bid - 520;
    const int x = cc & 7, j = cc >> 3;
    const int b = x + 8 * (j & 7);
    const int l0 = (j >> 3) * 64;
    {
        const int i = tid >> 1, h = tid & 1;
        const float* wrow = Wnb + (size_t)i * D + h * 64;
        const float* wa = waa + h * 64;
        float s = 0.f;
        #pragma unroll
        for (int k = 0; k < 16; ++k) {
            float4 a = *(const float4*)&wrow[k * 4];
            float4 b2 = *(const float4*)&wa[k * 4];
            s += a.x * b2.x + a.y * b2.y + a.z * b2.z + a.w * b2.w;
        }
        s += __shfl_xor(s, 1);
        if (h == 0) wvL[i] = s;
    }
    {
        float t = (tid < 128) ? bnb[tid] * waa[tid] : 0.f;
        #pragma unroll
        for (int o = 1; o < 64; o <<= 1) t += __shfl_xor(t, o);
        if ((tid & 63) == 0) ccL[tid >> 6] = t;
    }
    __syncthreads();
    const float c1 = ccL[0] + ccL[1] + ccL[2] + ccL[3];
    const int q = tid & 31, rg = tid >> 5;
    const float4 vq = *(const float4*)&wvL[q * 4];

    #pragma unroll
    for (int k = 0; k < 8; ++k) {
        const int l = rg * 8 + k;
        float4 xv = *(const float4*)&atom[((size_t)b * L + l0 + l) * D + q * 4];
        float dot = xv.x * vq.x + xv.y * vq.y + xv.z * vq.z + xv.w * vq.w;
        dot += __shfl_xor(dot, 1);  dot += __shfl_xor(dot, 2);
        dot += __shfl_xor(dot, 4);  dot += __shfl_xor(dot, 8);
        dot += __shfl_xor(dot, 16);
        union { ushort us[4]; uint2 u2; } pk;
        pk.us[0] = f2bf(xv.x); pk.us[1] = f2bf(xv.y);
        pk.us[2] = f2bf(xv.z); pk.us[3] = f2bf(xv.w);
        *(uint2*)&Ls[l][q * 4] = pk.u2;
        if (q == 0) {
            float msk = smask[(size_t)b * L + l0 + l];
            sM[(size_t)b * L + l0 + l] = (msk > -0.5f) ? (dot + c1) : -1e30f;
        }
    }
    __syncthreads();
    {
        const int d = tid >> 1, h = tid & 1;
        #pragma unroll
        for (int jj = 0; jj < 4; ++jj) {
            alignas(16) ushort tmp[8];
            #pragma unroll
            for (int m = 0; m < 8; ++m) tmp[m] = Ls[h * 32 + jj * 8 + m][d];
            *(int4*)&atomT[((size_t)(b * 128 + d) << 10) + l0 + h * 32 + jj * 8] =
                *(int4*)tmp;
        }
    }
}

// ---------------------------------------------------------------------------
// K2 "pv" (R11-verified): 512 blocks (b, lq, ah). Stage one 64 KB atomT tile
// via gl_lds (pre-swizzled source), ONE barrier, pure MFMA (A = P in regs).
// psum + bf16 partials (MFMA-native layout) to workspace. No fences.
// ---------------------------------------------------------------------------
__global__ __launch_bounds__(256, 2) void pv_kernel(
    const ushort* __restrict__ atomT, const float* __restrict__ sM_g,
    const float* __restrict__ smolG,
    uint2* __restrict__ PP, float* __restrict__ psumP) {
    __shared__ __align__(16) ushort Ta[128][256];
    __shared__ ushort eT[256], fT[256];

    const int bid = blockIdx.x;
    const int x = bid & 7, j = bid >> 3;
    const int b = x + 8 * (j & 7);
    const int rest = j >> 3;
    const int lq = rest >> 1, ah = rest & 1;
    const int tid = threadIdx.x;
    const int w = tid >> 6, lane = tid & 63;
    const int al = lane & 31, hi = lane >> 5;

    const ushort* atomTb = atomT + (size_t)b * D * L + lq * 256;

    #pragma unroll
    for (int q = 0; q < 16; ++q) {
        const int r0 = w * 32 + q * 2;
        const int r = r0 + hi;
        const ushort* g = atomTb + (size_t)r * L + ((al ^ (r & 15)) << 3);
        gl_lds16(g, (char*)&Ta[r0][0]);
    }
    {
        float s = sM_g[(size_t)b * L + lq * 256 + tid];
        eT[tid] = f2bf(__expf(s));
        fT[tid] = f2bf(__expf(NEG_SLOPE * s));
    }
    const int aG = ah * 128 + w * 32 + al;
    const float smv = smolG[(size_t)b * A + aG];
    const float ea = __expf(smv), fa = __expf(NEG_SLOPE * smv);
    __syncthreads();

    f32x16 acc[4] = {};
    float psum = 0.f;
    #pragma unroll 4
    for (int c = 0; c < 16; ++c) {
        const int lb = c * 16 + hi * 8;
        bf16x8 eb = *(const bf16x8*)&eT[lb];
        bf16x8 fb = *(const bf16x8*)&fT[lb];
        bf16x8 pf;
        #pragma unroll
        for (int jj = 0; jj < 8; ++jj) {
            float p_ = fmaxf(ea * bf2f((ushort)eb[jj]), fa * bf2f((ushort)fb[jj]));
            psum += p_;
            pf[jj] = (short)f2bf(p_);
        }
        const int ch = c * 2 + hi;
        #pragma unroll
        for (int dt = 0; dt < 4; ++dt) {
            const int row = dt * 32 + al;
            bf16x8 bf = *(const bf16x8*)((const char*)&Ta[0][0] + row * 512
                                         + ((ch ^ (row & 15)) << 4));
            acc[dt] = __builtin_amdgcn_mfma_f32_32x32x16_bf16(pf, bf, acc[dt], 0, 0, 0);
        }
    }

    psum += __shfl_xor(psum, 32);
    if (hi == 0) psumP[((size_t)b * 4 + lq) * A + aG] = psum;

    const size_t base0 = (((size_t)(b * 4 + lq) * 2 + ah) * 4 + w);
    #pragma unroll
    for (int dt = 0; dt < 4; ++dt) {
        #pragma unroll
        for (int rq = 0; rq < 4; ++rq) {
            union { ushort us[4]; uint2 u2; } pk;
            pk.us[0] = f2bf(acc[dt][rq * 4 + 0]);
            pk.us[1] = f2bf(acc[dt][rq * 4 + 1]);
            pk.us[2] = f2bf(acc[dt][rq * 4 + 2]);
            pk.us[3] = f2bf(acc[dt][rq * 4 + 3]);
            PP[((((base0 * 4 + dt) * 4 + rq) * 2 + hi) * 32) + al] = pk.u2;
        }
    }
}

// ---------------------------------------------------------------------------
// K3 "reduce" (R11-verified): 512 blocks (b, ah, at). Sum 4 lq partials ->
// TT bf16 (chunk-XOR) -> ctx = T.W MFMA + scale + LayerNorm -> out.
// ---------------------------------------------------------------------------
__global__ __launch_bounds__(256) void reduce_kernel(
    const uint2* __restrict__ PP, const float* __restrict__ psumP,
    const float* __restrict__ amask, const ushort* __restrict__ WB,
    const float* __restrict__ bnb,
    const float* __restrict__ gamma, const float* __restrict__ beta,
    float* __restrict__ out) {
    __shared__ __align__(16) ushort TT[32 * 128];
    __shared__ float gbL[256];
    __shared__ float lnP[4][2][16][2];

    const int bid = blockIdx.x;
    const int x = bid & 7, j = bid >> 3;
    const int b = x + 8 * (j & 7);
    const int rest = j >> 3;
    const int ah = rest >> 2, at = rest & 3;
    const int tid = threadIdx.x;
    const int w = tid >> 6, lane = tid & 63;
    const int la = lane & 15, kg = lane >> 4;
    const int xo = la & 7;
    const int aG0 = ah * 128 + at * 32;

    if (tid < 32)      ((float4*)gbL)[tid] = ((const float4*)gamma)[tid];
    else if (tid < 64) ((float4*)gbL)[tid] = ((const float4*)beta)[tid - 32];

    {
        const int rq = tid >> 6, hi2 = (tid >> 5) & 1, al2 = tid & 31;
        float s4[4][4];
        #pragma unroll
        for (int dt = 0; dt < 4; ++dt)
            #pragma unroll
            for (int e = 0; e < 4; ++e) s4[dt][e] = 0.f;
        #pragma unroll
        for (int lq = 0; lq < 4; ++lq) {
            const size_t bb = (((size_t)(b * 4 + lq) * 2 + ah) * 4 + at);
            #pragma unroll
            for (int dt = 0; dt < 4; ++dt) {
                uint2 v = PP[((((bb * 4 + dt) * 4 + rq) * 2 + hi2) * 32) + al2];
                s4[dt][0] += bf2f((ushort)(v.x & 0xffff));
                s4[dt][1] += bf2f((ushort)(v.x >> 16));
                s4[dt][2] += bf2f((ushort)(v.y & 0xffff));
                s4[dt][3] += bf2f((ushort)(v.y >> 16));
            }
        }
        #pragma unroll
        for (int dt = 0; dt < 4; ++dt) {
            const int d = dt * 32 + al2;
            const int cc = d >> 3;
            #pragma unroll
            for (int e = 0; e < 4; ++e) {
                const int arow = e + 8 * rq + 4 * hi2;
                *(ushort*)((char*)TT + arow * 256 + ((cc ^ (arow & 7)) << 4)
                           + (d & 7) * 2) = f2bf(s4[dt][e]);
            }
        }
    }

    bf16x8 wb0[4], wb1[4];
    {
        const ushort* wr0 = WB + (size_t)((2 * w) * 16 + la) * D + kg * 8;
        const ushort* wr1 = WB + (size_t)((2 * w + 1) * 16 + la) * D + kg * 8;
        #pragma unroll
        for (int ks = 0; ks < 4; ++ks) {
            wb0[ks] = *(const bf16x8*)&wr0[ks * 32];
            wb1[ks] = *(const bf16x8*)&wr1[ks * 32];
        }
    }
    float4 bias0 = *(const float4*)&bnb[w * 32 + kg * 4];
    float4 bias1 = *(const float4*)&bnb[w * 32 + 16 + kg * 4];
    const float amA = amask[(size_t)b * A + aG0 + la];
    const float amB = amask[(size_t)b * A + aG0 + 16 + la];
    float psA = 0.f, psB = 0.f;
    #pragma unroll
    for (int lq = 0; lq < 4; ++lq) {
        psA += psumP[((size_t)b * 4 + lq) * A + aG0 + la];
        psB += psumP[((size_t)b * 4 + lq) * A + aG0 + 16 + la];
    }
    __syncthreads();

    const char* TTc = (const char*)TT;
#define LDT(ROW_, KS_) (*(const bf16x8*)(TTc + (ROW_) * 256 + \
                         ((((KS_) * 4 + kg) ^ xo) << 4)))
    f32x4 cA0 = {}, cA1 = {}, cB0 = {}, cB1 = {};
    #pragma unroll
    for (int ks = 0; ks < 4; ++ks) {
        bf16x8 tA = LDT(la, ks);
        bf16x8 tB = LDT(la + 16, ks);
        cA0 = __builtin_amdgcn_mfma_f32_16x16x32_bf16(wb0[ks], tA, cA0, 0, 0, 0);
        cA1 = __builtin_amdgcn_mfma_f32_16x16x32_bf16(wb1[ks], tA, cA1, 0, 0, 0);
        cB0 = __builtin_amdgcn_mfma_f32_16x16x32_bf16(wb0[ks], tB, cB0, 0, 0, 0);
        cB1 = __builtin_amdgcn_mfma_f32_16x16x32_bf16(wb1[ks], tB, cB1, 0, 0, 0);
    }
#undef LDT

    const float scA = amA / psA, scB = amB / psB;
    float xA[8], xB[8];
    float s1A = 0.f, s2A = 0.f, s1B = 0.f, s2B = 0.f;
    const float* bp0 = (const float*)&bias0;
    const float* bp1 = (const float*)&bias1;
    #pragma unroll
    for (int r = 0; r < 4; ++r) {
        xA[r]     = cA0[r] * scA + amA * bp0[r];
        xA[4 + r] = cA1[r] * scA + amA * bp1[r];
        xB[r]     = cB0[r] * scB + amB * bp0[r];
        xB[4 + r] = cB1[r] * scB + amB * bp1[r];
        s1A += xA[r] + xA[4 + r]; s2A += xA[r] * xA[r] + xA[4 + r] * xA[4 + r];
        s1B += xB[r] + xB[4 + r]; s2B += xB[r] * xB[r] + xB[4 + r] * xB[4 + r];
    }
    s1A += __shfl_xor(s1A, 16); s1A += __shfl_xor(s1A, 32);
    s2A += __shfl_xor(s2A, 16); s2A += __shfl_xor(s2A, 32);
    s1B += __shfl_xor(s1B, 16); s1B += __shfl_xor(s1B, 32);
    s2B += __shfl_xor(s2B, 16); s2B += __shfl_xor(s2B, 32);
    if (lane < 16) {
        lnP[w][0][la][0] = s1A; lnP[w][0][la][1] = s2A;
        lnP[w][1][la][0] = s1B; lnP[w][1][la][1] = s2B;
    }
    __syncthreads();
    const float S1A = lnP[0][0][la][0] + lnP[1][0][la][0] + lnP[2][0][la][0] + lnP[3][0][la][0];
    const float S2A = lnP[0][0][la][1] + lnP[1][0][la][1] + lnP[2][0][la][1] + lnP[3][0][la][1];
    const float S1B = lnP[0][1][la][0] + lnP[1][1][la][0] + lnP[2][1][la][0] + lnP[3][1][la][0];
    const float S2B = lnP[0][1][la][1] + lnP[1][1][la][1] + lnP[2][1][la][1] + lnP[3][1][la][1];
    const float muA = S1A * (1.f / 128.f);
    const float rsA = rsqrtf(S2A * (1.f / 128.f) - muA * muA + LN_EPS);
    const float muB = S1B * (1.f / 128.f);
    const float rsB = rsqrtf(S2B * (1.f / 128.f) - muB * muB + LN_EPS);
    const size_t oA = ((size_t)b * A + aG0 + la) * D;
    const size_t oB = ((size_t)b * A + aG0 + 16 + la) * D;
    #pragma unroll
    for (int t = 0; t < 2; ++t) {
        const int e0 = w * 32 + t * 16 + kg * 4;
        float4 g4 = *(float4*)&gbL[e0];
        float4 b4 = *(float4*)&gbL[128 + e0];
        float4 ovA, ovB;
        const float* xpA = &xA[t * 4];
        const float* xpB = &xB[t * 4];
        ((float*)&ovA)[0] = (xpA[0] - muA) * rsA * g4.x + b4.x;
        ((float*)&ovA)[1] = (xpA[1] - muA) * rsA * g4.y + b4.y;
        ((float*)&ovA)[2] = (xpA[2] - muA) * rsA * g4.z + b4.z;
        ((float*)&ovA)[3] = (xpA[3] - muA) * rsA * g4.w + b4.w;
        ((float*)&ovB)[0] = (xpB[0] - muB) * rsB * g4.x + b4.x;
        ((float*)&ovB)[1] = (xpB[1] - muB) * rsB * g4.y + b4.y;
        ((float*)&ovB)[2] = (xpB[2] - muB) * rsB * g4.z + b4.z;
        ((float*)&ovB)[3] = (xpB[3] - muB) * rsB * g4.w + b4.w;
        *(float4*)&out[oA + e0] = ovA;
        *(float4*)&out[oB + e0] = ovB;
    }
}

// ---------------------------------------------------------------------------
extern "C" void kernel_launch(void* const* d_in, const int* in_sizes, int n_in,
                              void* d_out, int out_size, void* d_ws, size_t ws_size,
                              hipStream_t stream) {
    const float* molf  = (const float*)d_in[0];
    const float* atomf = (const float*)d_in[1];
    const float* amask = (const float*)d_in[2];
    const float* smask = (const float*)d_in[3];
    const float* W_mol = (const float*)d_in[4];
    const float* b_mol = (const float*)d_in[5];
    const float* W_nb  = (const float*)d_in[6];
    const float* b_nb  = (const float*)d_in[7];
    const float* w_am  = (const float*)d_in[8];
    const float* w_aa  = (const float*)d_in[9];
    const float* b_al  = (const float*)d_in[10];
    const float* gamma = (const float*)d_in[11];
    const float* beta  = (const float*)d_in[12];
    float* out = (float*)d_out;

    // ws: atomT bf16 [B*D*L] | PP uint2 [B*4*A*D/4] | sM [B*L] | smol [B*A]
    //     | psumP [B*4*A] | WB bf16 [D*D]
    ushort* atomT = (ushort*)d_ws;
    uint2* PP     = (uint2*)(atomT + (size_t)B * D * L);
    float* sM     = (float*)(PP + (size_t)B * 4 * A * D / 4);
    float* smolG  = sM + (size_t)B * L;
    float* psumP  = smolG + (size_t)B * A;
    ushort* WB    = (ushort*)(psumP + (size_t)B * 4 * A);

    pre_kernel<<<8 + 512 + 1024, 256, 0, stream>>>(
        molf, atomf, smask, W_mol, b_mol, w_am, b_al, W_nb, b_nb, w_aa,
        smolG, atomT, sM, WB);
    pv_kernel<<<512, 256, 0, stream>>>(atomT, sM, smolG, PP, psumP);
    reduce_kernel<<<512, 256, 0, stream>>>(PP, psumP, amask, WB, b_nb,
                                           gamma, beta, out);
}

// Round 15
// 45.080 us; speedup vs baseline: 4.3210x; 1.2107x over previous
//
#include <hip/hip_runtime.h>
#include <hip/hip_bf16.h>
#include <math.h>

#define NEG_SLOPE 0.2f
#define LN_EPS 1e-5f

constexpr int B = 64, A = 256, L = 1024, D = 128;

typedef float f32x4 __attribute__((ext_vector_type(4)));
typedef float f32x16 __attribute__((ext_vector_type(16)));
typedef short bf16x8 __attribute__((ext_vector_type(8)));

__device__ __forceinline__ ushort f2bf(float x) {
    __hip_bfloat16 h = __float2bfloat16(x);
    return *reinterpret_cast<ushort*>(&h);
}
__device__ __forceinline__ float bf2f(ushort x) {
    unsigned u = ((unsigned)x) << 16;
    return __uint_as_float(u);
}
__device__ __forceinline__ void gl_lds16(const void* g, void* l) {
    __builtin_amdgcn_global_load_lds(
        (const __attribute__((address_space(1))) unsigned int*)g,
        (__attribute__((address_space(3))) unsigned int*)l, 16, 0, 0);
}

// ---------------------------------------------------------------------------
// K1 "prep" (R11-verified): u = W_mol@w_am, v = W_nb@w_aa,
// c0 = b_mol.w_am + b_al, c1 = b_nb.w_aa, WB[e][d] = bf16(W_nb[d][e]).
// ---------------------------------------------------------------------------
__global__ void prep_kernel(const float* __restrict__ Wmol, const float* __restrict__ bmol,
                            const float* __restrict__ wam, const float* __restrict__ bal,
                            const float* __restrict__ Wnb, const float* __restrict__ bnb,
                            const float* __restrict__ waa,
                            float* __restrict__ u, float* __restrict__ v,
                            float* __restrict__ c0, float* __restrict__ c1,
                            ushort* __restrict__ WB) {
    __shared__ float redU[2], redV[2], redC0[2], redC1[2];
    const int i = blockIdx.x, e = threadIdx.x;
    const int lane = e & 63, wv = e >> 6;
    float wnb_ie = Wnb[i * D + e];
    WB[e * D + i] = f2bf(wnb_ie);
    float pu = Wmol[i * D + e] * wam[e];
    float pv = wnb_ie * waa[e];
    float q0 = (i == 0) ? bmol[e] * wam[e] : 0.f;
    float q1 = (i == 0) ? bnb[e] * waa[e] : 0.f;
    #pragma unroll
    for (int o = 1; o < 64; o <<= 1) {
        pu += __shfl_xor(pu, o); pv += __shfl_xor(pv, o);
        q0 += __shfl_xor(q0, o); q1 += __shfl_xor(q1, o);
    }
    if (lane == 0) { redU[wv] = pu; redV[wv] = pv; redC0[wv] = q0; redC1[wv] = q1; }
    __syncthreads();
    if (e == 0) {
        u[i] = redU[0] + redU[1];
        v[i] = redV[0] + redV[1];
        if (i == 0) { c0[0] = redC0[0] + redC0[1] + bal[0];
                      c1[0] = redC1[0] + redC1[1]; }
    }
}

// ---------------------------------------------------------------------------
// K2 "pre2": 512 smol blocks + 1024 trans blocks (both read precomputed u/v).
// ---------------------------------------------------------------------------
__global__ __launch_bounds__(256) void pre2_kernel(
    const float* __restrict__ molf, const float* __restrict__ atom,
    const float* __restrict__ smask,
    const float* __restrict__ u, const float* __restrict__ v,
    const float* __restrict__ c0p, const float* __restrict__ c1p,
    float* __restrict__ smolG, ushort* __restrict__ atomT,
    float* __restrict__ sM) {
    const int bid = blockIdx.x;
    const int tid = threadIdx.x;
    __shared__ __align__(16) ushort Ls[64][132];

    if (bid < 512) {
        // ---- smol: rows [bid*32, bid*32+32)
        const int r = tid >> 3, q = tid & 7;
        const int row = bid * 32 + r;
        const float* xp = molf + (size_t)row * D + q * 16;
        float p = 0.f;
        #pragma unroll
        for (int k = 0; k < 4; ++k) {
            float4 xv = *(const float4*)&xp[k * 4];
            float4 uv = *(const float4*)&u[q * 16 + k * 4];
            p += xv.x * uv.x + xv.y * uv.y + xv.z * uv.z + xv.w * uv.w;
        }
        p += __shfl_xor(p, 1); p += __shfl_xor(p, 2); p += __shfl_xor(p, 4);
        if (q == 0) smolG[row] = p + c0p[0];
        return;
    }

    // ---- trans chunk (XCD mapping preserved: 512 % 8 == 0)
    const int cc = bid - 512;
    const int x = cc & 7, j = cc >> 3;
    const int b = x + 8 * (j & 7);
    const int l0 = (j >> 3) * 64;
    const int q = tid & 31, rg = tid >> 5;
    const float4 vq = *(const float4*)&v[q * 4];
    const float c1 = c1p[0];

    #pragma unroll
    for (int k = 0; k < 8; ++k) {
        const int l = rg * 8 + k;
        float4 xv = *(const float4*)&atom[((size_t)b * L + l0 + l) * D + q * 4];
        float dot = xv.x * vq.x + xv.y * vq.y + xv.z * vq.z + xv.w * vq.w;
        dot += __shfl_xor(dot, 1);  dot += __shfl_xor(dot, 2);
        dot += __shfl_xor(dot, 4);  dot += __shfl_xor(dot, 8);
        dot += __shfl_xor(dot, 16);
        union { ushort us[4]; uint2 u2; } pk;
        pk.us[0] = f2bf(xv.x); pk.us[1] = f2bf(xv.y);
        pk.us[2] = f2bf(xv.z); pk.us[3] = f2bf(xv.w);
        *(uint2*)&Ls[l][q * 4] = pk.u2;
        if (q == 0) {
            float msk = smask[(size_t)b * L + l0 + l];
            sM[(size_t)b * L + l0 + l] = (msk > -0.5f) ? (dot + c1) : -1e30f;
        }
    }
    __syncthreads();
    {
        const int d = tid >> 1, h = tid & 1;
        #pragma unroll
        for (int jj = 0; jj < 4; ++jj) {
            alignas(16) ushort tmp[8];
            #pragma unroll
            for (int m = 0; m < 8; ++m) tmp[m] = Ls[h * 32 + jj * 8 + m][d];
            *(int4*)&atomT[((size_t)(b * 128 + d) << 10) + l0 + h * 32 + jj * 8] =
                *(int4*)tmp;
        }
    }
}

// ---------------------------------------------------------------------------
// K3 "pv_full": 256 blocks (b, aq = 64 a-rows), 1 block/CU, 4 waves.
// Wave w: a-group ga = w&1 (32 rows), l-half h2 = w>>1. Loops 4 x 64 KB
// atomT tiles, double-buffered gl_lds. After main loop: pairwise LDS combine
// (waves w/w+2), TT write, then ctx = T.W MFMA + scale + LN (R11-verified
// epilogue) for both 32-a groups. No PP / psumP / reduce kernel.
// ---------------------------------------------------------------------------
__global__ __launch_bounds__(256, 1) void pv_full_kernel(
    const ushort* __restrict__ atomT, const float* __restrict__ sM_g,
    const float* __restrict__ smolG, const float* __restrict__ amask,
    const ushort* __restrict__ WB, const float* __restrict__ bnb,
    const float* __restrict__ gamma, const float* __restrict__ beta,
    float* __restrict__ out) {
    __shared__ __align__(16) char arena[131072];         // 2 x 64 KB tiles
    __shared__ __align__(16) ushort eT[1024], fT[1024];  // 4 KB tables
    __shared__ float psumX[2][32], psumF[2][32];
    __shared__ float gbL[256];
    __shared__ float lnP[4][2][16][2];

    const int bid = blockIdx.x;
    const int x = bid & 7, j = bid >> 3;
    const int b = x + 8 * (j & 7);                       // XCD co-located
    const int aq = j >> 3;
    const int tid = threadIdx.x;
    const int w = tid >> 6, lane = tid & 63;
    const int al = lane & 31, hi = lane >> 5;
    const int la = lane & 15, kg = lane >> 4;
    const int xo = la & 7;
    const int ga = w & 1, h2 = w >> 1;

    const ushort* atomTb = atomT + (size_t)b * D * L;

#define STAGE(BUFOFF_, T_)                                                     \
    {                                                                          \
        _Pragma("unroll")                                                      \
        for (int q_ = 0; q_ < 16; ++q_) {                                      \
            const int r0_ = w * 32 + q_ * 2;                                   \
            const int r_ = r0_ + hi;                                           \
            const ushort* g_ = atomTb + (size_t)r_ * L + (T_) * 256            \
                               + ((al ^ (r_ & 15)) << 3);                      \
            gl_lds16(g_, arena + (BUFOFF_) + r0_ * 512);                       \
        }                                                                      \
    }

    STAGE(0, 0)

    if (tid < 32)      ((float4*)gbL)[tid] = ((const float4*)gamma)[tid];
    else if (tid < 64) ((float4*)gbL)[tid] = ((const float4*)beta)[tid - 32];
    {   // full-L softmax tables
        const int i4 = tid * 4;
        float4 sa = *(const float4*)&sM_g[(size_t)b * L + i4];
        eT[i4 + 0] = f2bf(__expf(sa.x)); eT[i4 + 1] = f2bf(__expf(sa.y));
        eT[i4 + 2] = f2bf(__expf(sa.z)); eT[i4 + 3] = f2bf(__expf(sa.w));
        fT[i4 + 0] = f2bf(__expf(NEG_SLOPE * sa.x));
        fT[i4 + 1] = f2bf(__expf(NEG_SLOPE * sa.y));
        fT[i4 + 2] = f2bf(__expf(NEG_SLOPE * sa.z));
        fT[i4 + 3] = f2bf(__expf(NEG_SLOPE * sa.w));
    }
    const int aG = aq * 64 + ga * 32 + al;
    const float smv = smolG[(size_t)b * A + aG];
    const float ea = __expf(smv), fa = __expf(NEG_SLOPE * smv);
    __syncthreads();   // tile 0 + tables ready

    f32x16 acc[4] = {};
    float psum = 0.f;

#define COMPUTE(BUFOFF_, T_)                                                   \
    {                                                                          \
        _Pragma("unroll")                                                      \
        for (int c_ = 0; c_ < 8; ++c_) {                                       \
            const int lbG_ = (T_) * 256 + h2 * 128 + c_ * 16 + hi * 8;         \
            bf16x8 eb = *(const bf16x8*)&eT[lbG_];                             \
            bf16x8 fb = *(const bf16x8*)&fT[lbG_];                             \
            bf16x8 pf;                                                         \
            _Pragma("unroll")                                                  \
            for (int jj = 0; jj < 8; ++jj) {                                   \
                float p_ = fmaxf(ea * bf2f((ushort)eb[jj]),                    \
                                 fa * bf2f((ushort)fb[jj]));                   \
                psum += p_;                                                    \
                pf[jj] = (short)f2bf(p_);                                      \
            }                                                                  \
            const int ch_ = h2 * 16 + c_ * 2 + hi;                             \
            _Pragma("unroll")                                                  \
            for (int dt_ = 0; dt_ < 4; ++dt_) {                                \
                const int row_ = dt_ * 32 + al;                                \
                bf16x8 bf = *(const bf16x8*)(arena + (BUFOFF_) + row_ * 512    \
                                             + ((ch_ ^ (row_ & 15)) << 4));    \
                acc[dt_] = __builtin_amdgcn_mfma_f32_32x32x16_bf16(            \
                    pf, bf, acc[dt_], 0, 0, 0);                                \
            }                                                                  \
        }                                                                      \
    }

    STAGE(65536, 1) COMPUTE(0, 0)     __syncthreads();
    STAGE(0, 2)     COMPUTE(65536, 1) __syncthreads();
    STAGE(65536, 3) COMPUTE(0, 2)     __syncthreads();
    COMPUTE(65536, 3)
#undef COMPUTE
#undef STAGE

    // GEMM operand prefetch (per-wave e-slice, group-independent)
    bf16x8 wb0[4], wb1[4];
    {
        const ushort* wr0 = WB + (size_t)((2 * w) * 16 + la) * D + kg * 8;
        const ushort* wr1 = WB + (size_t)((2 * w + 1) * 16 + la) * D + kg * 8;
        #pragma unroll
        for (int ks = 0; ks < 4; ++ks) {
            wb0[ks] = *(const bf16x8*)&wr0[ks * 32];
            wb1[ks] = *(const bf16x8*)&wr1[ks * 32];
        }
    }
    float4 bias0 = *(const float4*)&bnb[w * 32 + kg * 4];
    float4 bias1 = *(const float4*)&bnb[w * 32 + 16 + kg * 4];

    // ---- pairwise l-half combine: waves 2,3 publish; waves 0,1 own groups
    psum += __shfl_xor(psum, 32);
    float* cbuf = (float*)arena;                   // overlay buf0 (idle)
    if (w >= 2) {
        #pragma unroll
        for (int dt = 0; dt < 4; ++dt)
            #pragma unroll
            for (int rq = 0; rq < 4; ++rq)
                #pragma unroll
                for (int e = 0; e < 4; ++e) {
                    const int arow = e + 8 * rq + 4 * hi;
                    cbuf[(ga * 32 + arow) * 128 + dt * 32 + al] = acc[dt][rq * 4 + e];
                }
        if (lane < 32) psumX[ga][al] = psum;
    }
    __syncthreads();
    if (w < 2) {
        #pragma unroll
        for (int dt = 0; dt < 4; ++dt)
            #pragma unroll
            for (int rq = 0; rq < 4; ++rq)
                #pragma unroll
                for (int e = 0; e < 4; ++e) {
                    const int arow = e + 8 * rq + 4 * hi;
                    acc[dt][rq * 4 + e] += cbuf[(ga * 32 + arow) * 128 + dt * 32 + al];
                }
        psum += psumX[ga][al];
        if (lane < 32) psumF[ga][al] = psum;
        // TT write (raw ctx^T bf16, chunk-XOR; scale applied post-GEMM)
        char* TT = arena + 65536 + ga * 8192;      // overlay buf1 (idle)
        #pragma unroll
        for (int dt = 0; dt < 4; ++dt) {
            const int d = dt * 32 + al;
            const int ccd = d >> 3;
            #pragma unroll
            for (int rq = 0; rq < 4; ++rq)
                #pragma unroll
                for (int e = 0; e < 4; ++e) {
                    const int arow = e + 8 * rq + 4 * hi;
                    *(ushort*)(TT + arow * 256 + ((ccd ^ (arow & 7)) << 4)
                               + (d & 7) * 2) = f2bf(acc[dt][rq * 4 + e]);
                }
        }
    }
    __syncthreads();

    // ---- per-group: ctx = T.W (16 MFMA/wave) + scale + LayerNorm -> out
    #pragma unroll 1
    for (int g = 0; g < 2; ++g) {
        const char* TTc = arena + 65536 + g * 8192;
        const int aG0 = aq * 64 + g * 32;
#define LDT(ROW_, KS_) (*(const bf16x8*)(TTc + (ROW_) * 256 + \
                         ((((KS_) * 4 + kg) ^ xo) << 4)))
        f32x4 cA0 = {}, cA1 = {}, cB0 = {}, cB1 = {};
        #pragma unroll
        for (int ks = 0; ks < 4; ++ks) {
            bf16x8 tA = LDT(la, ks);
            bf16x8 tB = LDT(la + 16, ks);
            cA0 = __builtin_amdgcn_mfma_f32_16x16x32_bf16(wb0[ks], tA, cA0, 0, 0, 0);
            cA1 = __builtin_amdgcn_mfma_f32_16x16x32_bf16(wb1[ks], tA, cA1, 0, 0, 0);
            cB0 = __builtin_amdgcn_mfma_f32_16x16x32_bf16(wb0[ks], tB, cB0, 0, 0, 0);
            cB1 = __builtin_amdgcn_mfma_f32_16x16x32_bf16(wb1[ks], tB, cB1, 0, 0, 0);
        }
#undef LDT
        const float amA = amask[(size_t)b * A + aG0 + la];
        const float amB = amask[(size_t)b * A + aG0 + 16 + la];
        const float scA = amA / psumF[g][la];
        const float scB = amB / psumF[g][la + 16];
        float xA[8], xB[8];
        float s1A = 0.f, s2A = 0.f, s1B = 0.f, s2B = 0.f;
        const float* bp0 = (const float*)&bias0;
        const float* bp1 = (const float*)&bias1;
        #pragma unroll
        for (int r = 0; r < 4; ++r) {
            xA[r]     = cA0[r] * scA + amA * bp0[r];
            xA[4 + r] = cA1[r] * scA + amA * bp1[r];
            xB[r]     = cB0[r] * scB + amB * bp0[r];
            xB[4 + r] = cB1[r] * scB + amB * bp1[r];
            s1A += xA[r] + xA[4 + r]; s2A += xA[r] * xA[r] + xA[4 + r] * xA[4 + r];
            s1B += xB[r] + xB[4 + r]; s2B += xB[r] * xB[r] + xB[4 + r] * xB[4 + r];
        }
        s1A += __shfl_xor(s1A, 16); s1A += __shfl_xor(s1A, 32);
        s2A += __shfl_xor(s2A, 16); s2A += __shfl_xor(s2A, 32);
        s1B += __shfl_xor(s1B, 16); s1B += __shfl_xor(s1B, 32);
        s2B += __shfl_xor(s2B, 16); s2B += __shfl_xor(s2B, 32);
        if (lane < 16) {
            lnP[w][0][la][0] = s1A; lnP[w][0][la][1] = s2A;
            lnP[w][1][la][0] = s1B; lnP[w][1][la][1] = s2B;
        }
        __syncthreads();
        const float S1A = lnP[0][0][la][0] + lnP[1][0][la][0] + lnP[2][0][la][0] + lnP[3][0][la][0];
        const float S2A = lnP[0][0][la][1] + lnP[1][0][la][1] + lnP[2][0][la][1] + lnP[3][0][la][1];
        const float S1B = lnP[0][1][la][0] + lnP[1][1][la][0] + lnP[2][1][la][0] + lnP[3][1][la][0];
        const float S2B = lnP[0][1][la][1] + lnP[1][1][la][1] + lnP[2][1][la][1] + lnP[3][1][la][1];
        const float muA = S1A * (1.f / 128.f);
        const float rsA = rsqrtf(S2A * (1.f / 128.f) - muA * muA + LN_EPS);
        const float muB = S1B * (1.f / 128.f);
        const float rsB = rsqrtf(S2B * (1.f / 128.f) - muB * muB + LN_EPS);
        const size_t oA = ((size_t)b * A + aG0 + la) * D;
        const size_t oB = ((size_t)b * A + aG0 + 16 + la) * D;
        #pragma unroll
        for (int t = 0; t < 2; ++t) {
            const int e0 = w * 32 + t * 16 + kg * 4;
            float4 g4 = *(float4*)&gbL[e0];
            float4 b4 = *(float4*)&gbL[128 + e0];
            float4 ovA, ovB;
            const float* xpA = &xA[t * 4];
            const float* xpB = &xB[t * 4];
            ((float*)&ovA)[0] = (xpA[0] - muA) * rsA * g4.x + b4.x;
            ((float*)&ovA)[1] = (xpA[1] - muA) * rsA * g4.y + b4.y;
            ((float*)&ovA)[2] = (xpA[2] - muA) * rsA * g4.z + b4.z;
            ((float*)&ovA)[3] = (xpA[3] - muA) * rsA * g4.w + b4.w;
            ((float*)&ovB)[0] = (xpB[0] - muB) * rsB * g4.x + b4.x;
            ((float*)&ovB)[1] = (xpB[1] - muB) * rsB * g4.y + b4.y;
            ((float*)&ovB)[2] = (xpB[2] - muB) * rsB * g4.z + b4.z;
            ((float*)&ovB)[3] = (xpB[3] - muB) * rsB * g4.w + b4.w;
            *(float4*)&out[oA + e0] = ovA;
            *(float4*)&out[oB + e0] = ovB;
        }
        __syncthreads();
    }
}

// ---------------------------------------------------------------------------
extern "C" void kernel_launch(void* const* d_in, const int* in_sizes, int n_in,
                              void* d_out, int out_size, void* d_ws, size_t ws_size,
                              hipStream_t stream) {
    const float* molf  = (const float*)d_in[0];
    const float* atomf = (const float*)d_in[1];
    const float* amask = (const float*)d_in[2];
    const float* smask = (const float*)d_in[3];
    const float* W_mol = (const float*)d_in[4];
    const float* b_mol = (const float*)d_in[5];
    const float* W_nb  = (const float*)d_in[6];
    const float* b_nb  = (const float*)d_in[7];
    const float* w_am  = (const float*)d_in[8];
    const float* w_aa  = (const float*)d_in[9];
    const float* b_al  = (const float*)d_in[10];
    const float* gamma = (const float*)d_in[11];
    const float* beta  = (const float*)d_in[12];
    float* out = (float*)d_out;

    // ws: atomT bf16 [B*D*L] | sM [B*L] | smol [B*A] | u,v [D] | c0,c1 | WB
    ushort* atomT = (ushort*)d_ws;
    float* sM     = (float*)(atomT + (size_t)B * D * L);
    float* smolG  = sM + (size_t)B * L;
    float* u_ws   = smolG + (size_t)B * A;
    float* v_ws   = u_ws + D;
    float* c0_ws  = v_ws + D;
    float* c1_ws  = c0_ws + 1;
    ushort* WB    = (ushort*)(c1_ws + 1);

    prep_kernel<<<128, 128, 0, stream>>>(W_mol, b_mol, w_am, b_al, W_nb, b_nb,
                                         w_aa, u_ws, v_ws, c0_ws, c1_ws, WB);
    pre2_kernel<<<512 + 1024, 256, 0, stream>>>(molf, atomf, smask, u_ws, v_ws,
                                                c0_ws, c1_ws, smolG, atomT, sM);
    pv_full_kernel<<<256, 256, 0, stream>>>(atomT, sM, smolG, amask, WB, b_nb,
                                            gamma, beta, out);
}

// Round 16
// 42.557 us; speedup vs baseline: 4.5772x; 1.0593x over previous
//
#include <hip/hip_runtime.h>
#include <hip/hip_bf16.h>
#include <math.h>

#define NEG_SLOPE 0.2f
#define LN_EPS 1e-5f

constexpr int B = 64, A = 256, L = 1024, D = 128;

typedef float f32x4 __attribute__((ext_vector_type(4)));
typedef float f32x16 __attribute__((ext_vector_type(16)));
typedef short bf16x8 __attribute__((ext_vector_type(8)));

__device__ __forceinline__ ushort f2bf(float x) {
    __hip_bfloat16 h = __float2bfloat16(x);
    return *reinterpret_cast<ushort*>(&h);
}
__device__ __forceinline__ float bf2f(ushort x) {
    unsigned u = ((unsigned)x) << 16;
    return __uint_as_float(u);
}
__device__ __forceinline__ void gl_lds16(const void* g, void* l) {
    __builtin_amdgcn_global_load_lds(
        (const __attribute__((address_space(1))) unsigned int*)g,
        (__attribute__((address_space(3))) unsigned int*)l, 16, 0, 0);
}

// ---------------------------------------------------------------------------
// K1 "prep" (R11-verified): u, v, c0, c1, WB.
// ---------------------------------------------------------------------------
__global__ void prep_kernel(const float* __restrict__ Wmol, const float* __restrict__ bmol,
                            const float* __restrict__ wam, const float* __restrict__ bal,
                            const float* __restrict__ Wnb, const float* __restrict__ bnb,
                            const float* __restrict__ waa,
                            float* __restrict__ u, float* __restrict__ v,
                            float* __restrict__ c0, float* __restrict__ c1,
                            ushort* __restrict__ WB) {
    __shared__ float redU[2], redV[2], redC0[2], redC1[2];
    const int i = blockIdx.x, e = threadIdx.x;
    const int lane = e & 63, wv = e >> 6;
    float wnb_ie = Wnb[i * D + e];
    WB[e * D + i] = f2bf(wnb_ie);
    float pu = Wmol[i * D + e] * wam[e];
    float pv = wnb_ie * waa[e];
    float q0 = (i == 0) ? bmol[e] * wam[e] : 0.f;
    float q1 = (i == 0) ? bnb[e] * waa[e] : 0.f;
    #pragma unroll
    for (int o = 1; o < 64; o <<= 1) {
        pu += __shfl_xor(pu, o); pv += __shfl_xor(pv, o);
        q0 += __shfl_xor(q0, o); q1 += __shfl_xor(q1, o);
    }
    if (lane == 0) { redU[wv] = pu; redV[wv] = pv; redC0[wv] = q0; redC1[wv] = q1; }
    __syncthreads();
    if (e == 0) {
        u[i] = redU[0] + redU[1];
        v[i] = redV[0] + redV[1];
        if (i == 0) { c0[0] = redC0[0] + redC0[1] + bal[0];
                      c1[0] = redC1[0] + redC1[1]; }
    }
}

// ---------------------------------------------------------------------------
// K2 "pre2" (R15-verified): 512 smol blocks + 1024 trans blocks.
// ---------------------------------------------------------------------------
__global__ __launch_bounds__(256) void pre2_kernel(
    const float* __restrict__ molf, const float* __restrict__ atom,
    const float* __restrict__ smask,
    const float* __restrict__ u, const float* __restrict__ v,
    const float* __restrict__ c0p, const float* __restrict__ c1p,
    float* __restrict__ smolG, ushort* __restrict__ atomT,
    float* __restrict__ sM) {
    const int bid = blockIdx.x;
    const int tid = threadIdx.x;
    __shared__ __align__(16) ushort Ls[64][132];

    if (bid < 512) {
        const int r = tid >> 3, q = tid & 7;
        const int row = bid * 32 + r;
        const float* xp = molf + (size_t)row * D + q * 16;
        float p = 0.f;
        #pragma unroll
        for (int k = 0; k < 4; ++k) {
            float4 xv = *(const float4*)&xp[k * 4];
            float4 uv = *(const float4*)&u[q * 16 + k * 4];
            p += xv.x * uv.x + xv.y * uv.y + xv.z * uv.z + xv.w * uv.w;
        }
        p += __shfl_xor(p, 1); p += __shfl_xor(p, 2); p += __shfl_xor(p, 4);
        if (q == 0) smolG[row] = p + c0p[0];
        return;
    }

    const int cc = bid - 512;
    const int x = cc & 7, j = cc >> 3;
    const int b = x + 8 * (j & 7);
    const int l0 = (j >> 3) * 64;
    const int q = tid & 31, rg = tid >> 5;
    const float4 vq = *(const float4*)&v[q * 4];
    const float c1 = c1p[0];

    #pragma unroll
    for (int k = 0; k < 8; ++k) {
        const int l = rg * 8 + k;
        float4 xv = *(const float4*)&atom[((size_t)b * L + l0 + l) * D + q * 4];
        float dot = xv.x * vq.x + xv.y * vq.y + xv.z * vq.z + xv.w * vq.w;
        dot += __shfl_xor(dot, 1);  dot += __shfl_xor(dot, 2);
        dot += __shfl_xor(dot, 4);  dot += __shfl_xor(dot, 8);
        dot += __shfl_xor(dot, 16);
        union { ushort us[4]; uint2 u2; } pk;
        pk.us[0] = f2bf(xv.x); pk.us[1] = f2bf(xv.y);
        pk.us[2] = f2bf(xv.z); pk.us[3] = f2bf(xv.w);
        *(uint2*)&Ls[l][q * 4] = pk.u2;
        if (q == 0) {
            float msk = smask[(size_t)b * L + l0 + l];
            sM[(size_t)b * L + l0 + l] = (msk > -0.5f) ? (dot + c1) : -1e30f;
        }
    }
    __syncthreads();
    {
        const int d = tid >> 1, h = tid & 1;
        #pragma unroll
        for (int jj = 0; jj < 4; ++jj) {
            alignas(16) ushort tmp[8];
            #pragma unroll
            for (int m = 0; m < 8; ++m) tmp[m] = Ls[h * 32 + jj * 8 + m][d];
            *(int4*)&atomT[((size_t)(b * 128 + d) << 10) + l0 + h * 32 + jj * 8] =
                *(int4*)tmp;
        }
    }
}

// ---------------------------------------------------------------------------
// K3 "pv_full" v2: 256 blocks (b, aq = 64 a) x 512 threads (8 waves,
// 2 waves/SIMD). Wave = (ga = w&1: a-32-group, h2 = w>>1: l-quarter of each
// 256-l tile). 4 x 64 KB tiles, dbuf gl_lds. l-combine: 2-round pairwise
// LDS tree -> waves 0,1 hold group totals -> TT (overlay buf1) ->
// ctx = T.W MFMA + scale + LN on all 8 waves (2 groups x 4 e-slices).
// Per-lane fragment math identical to R15 (passed).
// ---------------------------------------------------------------------------
__global__ __launch_bounds__(512, 2) void pv_full_kernel(
    const ushort* __restrict__ atomT, const float* __restrict__ sM_g,
    const float* __restrict__ smolG, const float* __restrict__ amask,
    const ushort* __restrict__ WB, const float* __restrict__ bnb,
    const float* __restrict__ gamma, const float* __restrict__ beta,
    float* __restrict__ out) {
    __shared__ __align__(16) char arena[131072];         // 2 x 64 KB tiles
    __shared__ __align__(16) ushort eT[1024], fT[1024];  // 4 KB tables
    __shared__ float psums[4][2][32];                    // [h2][ga][a]
    __shared__ float gbL[256];
    __shared__ float lnP[2][4][2][16][2];

    const int bid = blockIdx.x;
    const int x = bid & 7, j = bid >> 3;
    const int b = x + 8 * (j & 7);                       // XCD co-located
    const int aq = j >> 3;
    const int tid = threadIdx.x;
    const int w = tid >> 6, lane = tid & 63;
    const int al = lane & 31, hi = lane >> 5;
    const int la = lane & 15, kg = lane >> 4;
    const int xo = la & 7;
    const int ga = w & 1, h2 = w >> 1;

    const ushort* atomTb = atomT + (size_t)b * D * L;

#define STAGE(BUFOFF_, T_)                                                     \
    {                                                                          \
        _Pragma("unroll")                                                      \
        for (int q_ = 0; q_ < 8; ++q_) {                                       \
            const int r0_ = w * 16 + q_ * 2;                                   \
            const int r_ = r0_ + hi;                                           \
            const ushort* g_ = atomTb + (size_t)r_ * L + (T_) * 256            \
                               + ((al ^ (r_ & 15)) << 3);                      \
            gl_lds16(g_, arena + (BUFOFF_) + r0_ * 512);                       \
        }                                                                      \
    }

    STAGE(0, 0)

    if (tid < 32)      ((float4*)gbL)[tid] = ((const float4*)gamma)[tid];
    else if (tid < 64) ((float4*)gbL)[tid] = ((const float4*)beta)[tid - 32];
    {   // full-L softmax tables (512 threads x 2)
        const int i2 = tid * 2;
        float2 sa = *(const float2*)&sM_g[(size_t)b * L + i2];
        eT[i2 + 0] = f2bf(__expf(sa.x)); eT[i2 + 1] = f2bf(__expf(sa.y));
        fT[i2 + 0] = f2bf(__expf(NEG_SLOPE * sa.x));
        fT[i2 + 1] = f2bf(__expf(NEG_SLOPE * sa.y));
    }
    const int aG = aq * 64 + ga * 32 + al;
    const float smv = smolG[(size_t)b * A + aG];
    const float ea = __expf(smv), fa = __expf(NEG_SLOPE * smv);
    __syncthreads();   // tile 0 + tables ready

    f32x16 acc[4] = {};
    float psum = 0.f;

#define COMPUTE(BUFOFF_, T_)                                                   \
    {                                                                          \
        _Pragma("unroll")                                                      \
        for (int c_ = 0; c_ < 4; ++c_) {                                       \
            const int lbG_ = (T_) * 256 + h2 * 64 + c_ * 16 + hi * 8;          \
            bf16x8 eb = *(const bf16x8*)&eT[lbG_];                             \
            bf16x8 fb = *(const bf16x8*)&fT[lbG_];                             \
            bf16x8 pf;                                                         \
            _Pragma("unroll")                                                  \
            for (int jj = 0; jj < 8; ++jj) {                                   \
                float p_ = fmaxf(ea * bf2f((ushort)eb[jj]),                    \
                                 fa * bf2f((ushort)fb[jj]));                   \
                psum += p_;                                                    \
                pf[jj] = (short)f2bf(p_);                                      \
            }                                                                  \
            const int ch_ = h2 * 8 + c_ * 2 + hi;                              \
            _Pragma("unroll")                                                  \
            for (int dt_ = 0; dt_ < 4; ++dt_) {                                \
                const int row_ = dt_ * 32 + al;                                \
                bf16x8 bf = *(const bf16x8*)(arena + (BUFOFF_) + row_ * 512    \
                                             + ((ch_ ^ (row_ & 15)) << 4));    \
                acc[dt_] = __builtin_amdgcn_mfma_f32_32x32x16_bf16(            \
                    pf, bf, acc[dt_], 0, 0, 0);                                \
            }                                                                  \
        }                                                                      \
    }

    STAGE(65536, 1) COMPUTE(0, 0)     __syncthreads();
    STAGE(0, 2)     COMPUTE(65536, 1) __syncthreads();
    STAGE(65536, 3) COMPUTE(0, 2)     __syncthreads();
    COMPUTE(65536, 3)
#undef COMPUTE
#undef STAGE

    // psum: combine hi halves; publish per (h2, ga)
    psum += __shfl_xor(psum, 32);
    if (lane < 32) psums[h2][ga][al] = psum;

    // ---- l-combine round 1: waves h2>=2 publish fp32 planes into buf0
    float* cbuf = (float*)arena;     // 4 slots x [32 a][128 d] = 64 KB (buf0)
    if (h2 >= 2) {
        float* pl = cbuf + ((h2 - 2) * 2 + ga) * 4096;
        #pragma unroll
        for (int dt = 0; dt < 4; ++dt)
            #pragma unroll
            for (int rq = 0; rq < 4; ++rq)
                #pragma unroll
                for (int e = 0; e < 4; ++e) {
                    const int arow = e + 8 * rq + 4 * hi;
                    pl[arow * 128 + dt * 32 + al] = acc[dt][rq * 4 + e];
                }
    }
    __syncthreads();
    if (h2 < 2) {
        const float* pl = cbuf + (h2 * 2 + ga) * 4096;
        #pragma unroll
        for (int dt = 0; dt < 4; ++dt)
            #pragma unroll
            for (int rq = 0; rq < 4; ++rq)
                #pragma unroll
                for (int e = 0; e < 4; ++e) {
                    const int arow = e + 8 * rq + 4 * hi;
                    acc[dt][rq * 4 + e] += pl[arow * 128 + dt * 32 + al];
                }
    }
    __syncthreads();
    // ---- round 2: waves h2==1 publish; waves h2==0 add -> group totals
    if (h2 == 1) {
        float* pl = cbuf + ga * 4096;
        #pragma unroll
        for (int dt = 0; dt < 4; ++dt)
            #pragma unroll
            for (int rq = 0; rq < 4; ++rq)
                #pragma unroll
                for (int e = 0; e < 4; ++e) {
                    const int arow = e + 8 * rq + 4 * hi;
                    pl[arow * 128 + dt * 32 + al] = acc[dt][rq * 4 + e];
                }
    }
    __syncthreads();
    if (h2 == 0) {
        const float* pl = cbuf + ga * 4096;
        char* TT = arena + 65536 + ga * 8192;   // overlay buf1 (dead)
        #pragma unroll
        for (int dt = 0; dt < 4; ++dt) {
            const int d = dt * 32 + al;
            const int ccd = d >> 3;
            #pragma unroll
            for (int rq = 0; rq < 4; ++rq)
                #pragma unroll
                for (int e = 0; e < 4; ++e) {
                    const int arow = e + 8 * rq + 4 * hi;
                    float t = acc[dt][rq * 4 + e] + pl[arow * 128 + dt * 32 + al];
                    *(ushort*)(TT + arow * 256 + ((ccd ^ (arow & 7)) << 4)
                               + (d & 7) * 2) = f2bf(t);
                }
        }
    }
    __syncthreads();

    // ---- epilogue: g2 = w>>2 (a-group), ww = w&3 (e-slice)
    const int g2 = w >> 2, ww = w & 3;
    bf16x8 wb0[4], wb1[4];
    {
        const ushort* wr0 = WB + (size_t)((2 * ww) * 16 + la) * D + kg * 8;
        const ushort* wr1 = WB + (size_t)((2 * ww + 1) * 16 + la) * D + kg * 8;
        #pragma unroll
        for (int ks = 0; ks < 4; ++ks) {
            wb0[ks] = *(const bf16x8*)&wr0[ks * 32];
            wb1[ks] = *(const bf16x8*)&wr1[ks * 32];
        }
    }
    float4 bias0 = *(const float4*)&bnb[ww * 32 + kg * 4];
    float4 bias1 = *(const float4*)&bnb[ww * 32 + 16 + kg * 4];
    const int aG0 = aq * 64 + g2 * 32;
    const char* TTc = arena + 65536 + g2 * 8192;
#define LDT(ROW_, KS_) (*(const bf16x8*)(TTc + (ROW_) * 256 + \
                         ((((KS_) * 4 + kg) ^ xo) << 4)))
    f32x4 cA0 = {}, cA1 = {}, cB0 = {}, cB1 = {};
    #pragma unroll
    for (int ks = 0; ks < 4; ++ks) {
        bf16x8 tA = LDT(la, ks);
        bf16x8 tB = LDT(la + 16, ks);
        cA0 = __builtin_amdgcn_mfma_f32_16x16x32_bf16(wb0[ks], tA, cA0, 0, 0, 0);
        cA1 = __builtin_amdgcn_mfma_f32_16x16x32_bf16(wb1[ks], tA, cA1, 0, 0, 0);
        cB0 = __builtin_amdgcn_mfma_f32_16x16x32_bf16(wb0[ks], tB, cB0, 0, 0, 0);
        cB1 = __builtin_amdgcn_mfma_f32_16x16x32_bf16(wb1[ks], tB, cB1, 0, 0, 0);
    }
#undef LDT

    const float amA = amask[(size_t)b * A + aG0 + la];
    const float amB = amask[(size_t)b * A + aG0 + 16 + la];
    const float psA = psums[0][g2][la] + psums[1][g2][la]
                    + psums[2][g2][la] + psums[3][g2][la];
    const float psB = psums[0][g2][la + 16] + psums[1][g2][la + 16]
                    + psums[2][g2][la + 16] + psums[3][g2][la + 16];
    const float scA = amA / psA, scB = amB / psB;
    float xA[8], xB[8];
    float s1A = 0.f, s2A = 0.f, s1B = 0.f, s2B = 0.f;
    const float* bp0 = (const float*)&bias0;
    const float* bp1 = (const float*)&bias1;
    #pragma unroll
    for (int r = 0; r < 4; ++r) {
        xA[r]     = cA0[r] * scA + amA * bp0[r];
        xA[4 + r] = cA1[r] * scA + amA * bp1[r];
        xB[r]     = cB0[r] * scB + amB * bp0[r];
        xB[4 + r] = cB1[r] * scB + amB * bp1[r];
        s1A += xA[r] + xA[4 + r]; s2A += xA[r] * xA[r] + xA[4 + r] * xA[4 + r];
        s1B += xB[r] + xB[4 + r]; s2B += xB[r] * xB[r] + xB[4 + r] * xB[4 + r];
    }
    s1A += __shfl_xor(s1A, 16); s1A += __shfl_xor(s1A, 32);
    s2A += __shfl_xor(s2A, 16); s2A += __shfl_xor(s2A, 32);
    s1B += __shfl_xor(s1B, 16); s1B += __shfl_xor(s1B, 32);
    s2B += __shfl_xor(s2B, 16); s2B += __shfl_xor(s2B, 32);
    if (lane < 16) {
        lnP[g2][ww][0][la][0] = s1A; lnP[g2][ww][0][la][1] = s2A;
        lnP[g2][ww][1][la][0] = s1B; lnP[g2][ww][1][la][1] = s2B;
    }
    __syncthreads();
    const float S1A = lnP[g2][0][0][la][0] + lnP[g2][1][0][la][0]
                    + lnP[g2][2][0][la][0] + lnP[g2][3][0][la][0];
    const float S2A = lnP[g2][0][0][la][1] + lnP[g2][1][0][la][1]
                    + lnP[g2][2][0][la][1] + lnP[g2][3][0][la][1];
    const float S1B = lnP[g2][0][1][la][0] + lnP[g2][1][1][la][0]
                    + lnP[g2][2][1][la][0] + lnP[g2][3][1][la][0];
    const float S2B = lnP[g2][0][1][la][1] + lnP[g2][1][1][la][1]
                    + lnP[g2][2][1][la][1] + lnP[g2][3][1][la][1];
    const float muA = S1A * (1.f / 128.f);
    const float rsA = rsqrtf(S2A * (1.f / 128.f) - muA * muA + LN_EPS);
    const float muB = S1B * (1.f / 128.f);
    const float rsB = rsqrtf(S2B * (1.f / 128.f) - muB * muB + LN_EPS);
    const size_t oA = ((size_t)b * A + aG0 + la) * D;
    const size_t oB = ((size_t)b * A + aG0 + 16 + la) * D;
    #pragma unroll
    for (int t = 0; t < 2; ++t) {
        const int e0 = ww * 32 + t * 16 + kg * 4;
        float4 g4 = *(float4*)&gbL[e0];
        float4 b4 = *(float4*)&gbL[128 + e0];
        float4 ovA, ovB;
        const float* xpA = &xA[t * 4];
        const float* xpB = &xB[t * 4];
        ((float*)&ovA)[0] = (xpA[0] - muA) * rsA * g4.x + b4.x;
        ((float*)&ovA)[1] = (xpA[1] - muA) * rsA * g4.y + b4.y;
        ((float*)&ovA)[2] = (xpA[2] - muA) * rsA * g4.z + b4.z;
        ((float*)&ovA)[3] = (xpA[3] - muA) * rsA * g4.w + b4.w;
        ((float*)&ovB)[0] = (xpB[0] - muB) * rsB * g4.x + b4.x;
        ((float*)&ovB)[1] = (xpB[1] - muB) * rsB * g4.y + b4.y;
        ((float*)&ovB)[2] = (xpB[2] - muB) * rsB * g4.z + b4.z;
        ((float*)&ovB)[3] = (xpB[3] - muB) * rsB * g4.w + b4.w;
        *(float4*)&out[oA + e0] = ovA;
        *(float4*)&out[oB + e0] = ovB;
    }
}

// ---------------------------------------------------------------------------
extern "C" void kernel_launch(void* const* d_in, const int* in_sizes, int n_in,
                              void* d_out, int out_size, void* d_ws, size_t ws_size,
                              hipStream_t stream) {
    const float* molf  = (const float*)d_in[0];
    const float* atomf = (const float*)d_in[1];
    const float* amask = (const float*)d_in[2];
    const float* smask = (const float*)d_in[3];
    const float* W_mol = (const float*)d_in[4];
    const float* b_mol = (const float*)d_in[5];
    const float* W_nb  = (const float*)d_in[6];
    const float* b_nb  = (const float*)d_in[7];
    const float* w_am  = (const float*)d_in[8];
    const float* w_aa  = (const float*)d_in[9];
    const float* b_al  = (const float*)d_in[10];
    const float* gamma = (const float*)d_in[11];
    const float* beta  = (const float*)d_in[12];
    float* out = (float*)d_out;

    // ws: atomT bf16 [B*D*L] | sM [B*L] | smol [B*A] | u,v [D] | c0,c1 | WB
    ushort* atomT = (ushort*)d_ws;
    float* sM     = (float*)(atomT + (size_t)B * D * L);
    float* smolG  = sM + (size_t)B * L;
    float* u_ws   = smolG + (size_t)B * A;
    float* v_ws   = u_ws + D;
    float* c0_ws  = v_ws + D;
    float* c1_ws  = c0_ws + 1;
    ushort* WB    = (ushort*)(c1_ws + 1);

    prep_kernel<<<128, 128, 0, stream>>>(W_mol, b_mol, w_am, b_al, W_nb, b_nb,
                                         w_aa, u_ws, v_ws, c0_ws, c1_ws, WB);
    pre2_kernel<<<512 + 1024, 256, 0, stream>>>(molf, atomf, smask, u_ws, v_ws,
                                                c0_ws, c1_ws, smolG, atomT, sM);
    pv_full_kernel<<<256, 512, 0, stream>>>(atomT, sM, smolG, amask, WB, b_nb,
                                            gamma, beta, out);
}

// Round 17
// 39.815 us; speedup vs baseline: 4.8924x; 1.0689x over previous
//
#include <hip/hip_runtime.h>
#include <hip/hip_bf16.h>
#include <math.h>

#define NEG_SLOPE 0.2f
#define LN_EPS 1e-5f

constexpr int B = 64, A = 256, L = 1024, D = 128;

typedef float f32x4 __attribute__((ext_vector_type(4)));
typedef float f32x16 __attribute__((ext_vector_type(16)));
typedef short bf16x8 __attribute__((ext_vector_type(8)));

__device__ __forceinline__ ushort f2bf(float x) {
    __hip_bfloat16 h = __float2bfloat16(x);
    return *reinterpret_cast<ushort*>(&h);
}
__device__ __forceinline__ float bf2f(ushort x) {
    unsigned u = ((unsigned)x) << 16;
    return __uint_as_float(u);
}

// ---------------------------------------------------------------------------
// K1 "prep" (R11-verified): u = W_mol@w_am, v = W_nb@w_aa,
// c0 = b_mol.w_am + b_al, c1 = b_nb.w_aa, WB[e][d] = bf16(W_nb[d][e]).
// ---------------------------------------------------------------------------
__global__ void prep_kernel(const float* __restrict__ Wmol, const float* __restrict__ bmol,
                            const float* __restrict__ wam, const float* __restrict__ bal,
                            const float* __restrict__ Wnb, const float* __restrict__ bnb,
                            const float* __restrict__ waa,
                            float* __restrict__ u, float* __restrict__ v,
                            float* __restrict__ c0, float* __restrict__ c1,
                            ushort* __restrict__ WB) {
    __shared__ float redU[2], redV[2], redC0[2], redC1[2];
    const int i = blockIdx.x, e = threadIdx.x;
    const int lane = e & 63, wv = e >> 6;
    float wnb_ie = Wnb[i * D + e];
    WB[e * D + i] = f2bf(wnb_ie);
    float pu = Wmol[i * D + e] * wam[e];
    float pv = wnb_ie * waa[e];
    float q0 = (i == 0) ? bmol[e] * wam[e] : 0.f;
    float q1 = (i == 0) ? bnb[e] * waa[e] : 0.f;
    #pragma unroll
    for (int o = 1; o < 64; o <<= 1) {
        pu += __shfl_xor(pu, o); pv += __shfl_xor(pv, o);
        q0 += __shfl_xor(q0, o); q1 += __shfl_xor(q1, o);
    }
    if (lane == 0) { redU[wv] = pu; redV[wv] = pv; redC0[wv] = q0; redC1[wv] = q1; }
    __syncthreads();
    if (e == 0) {
        u[i] = redU[0] + redU[1];
        v[i] = redV[0] + redV[1];
        if (i == 0) { c0[0] = redC0[0] + redC0[1] + bal[0];
                      c1[0] = redC1[0] + redC1[1]; }
    }
}

// ---------------------------------------------------------------------------
// K2 "pv" v3 (self-contained): 512 blocks (b, lq, ah), 256 thr, 2 blocks/CU.
//  - inline s_mol slice (2 thr/row dot with u)
//  - per 32-l chunk: read raw atom fp32, s_atm dot + masked e/f tables,
//    bf16 LDS bounce -> transposed swizzled Ta[128 d][256 l]
//  - then R11-verified MFMA loop + psum + bf16 PP partials.
// No atomT / sM / smolG intermediates; trans kernel eliminated.
// ---------------------------------------------------------------------------
__global__ __launch_bounds__(256, 2) void pv_kernel(
    const float* __restrict__ molf, const float* __restrict__ atom,
    const float* __restrict__ smask,
    const float* __restrict__ u, const float* __restrict__ v,
    const float* __restrict__ c0p, const float* __restrict__ c1p,
    uint2* __restrict__ PP, float* __restrict__ psumP) {
    __shared__ __align__(16) ushort Ta[128][256];   // 64 KB swizzled [d][l]
    __shared__ __align__(16) ushort Ls[32][132];    // 8.25 KB natural bounce
    __shared__ float uL[128], vL[128], smL[128];
    __shared__ ushort eT[256], fT[256];

    const int bid = blockIdx.x;
    const int x = bid & 7, j = bid >> 3;
    const int b = x + 8 * (j & 7);                  // XCD-spread
    const int rest = j >> 3;
    const int lq = rest >> 1, ah = rest & 1;
    const int tid = threadIdx.x;
    const int w = tid >> 6, lane = tid & 63;
    const int al = lane & 31, hi = lane >> 5;

    if (tid < 128) { uL[tid] = u[tid]; vL[tid] = v[tid]; }
    __syncthreads();

    // ---- phase 0: s_mol slice (rows ah*128 .. +128), 2 threads per row
    {
        const int r = tid >> 1, h = tid & 1;
        const float* xp = molf + ((size_t)b * A + ah * 128 + r) * D + h * 64;
        float p = 0.f;
        #pragma unroll
        for (int k = 0; k < 16; ++k) {
            float4 xv = *(const float4*)&xp[k * 4];
            float4 uv = *(const float4*)&uL[h * 64 + k * 4];
            p += xv.x * uv.x + xv.y * uv.y + xv.z * uv.z + xv.w * uv.w;
        }
        p += __shfl_xor(p, 1);
        if (h == 0) smL[r] = p + c0p[0];
    }

    const float c1 = c1p[0];

    // ---- chunk loop: 8 x 32 l -> Ta (transposed, swizzled) + tables
    #pragma unroll 1
    for (int c = 0; c < 8; ++c) {
        {
            const int lr = tid >> 3, q = tid & 7;
            const int l = lq * 256 + c * 32 + lr;
            const float* ap = atom + ((size_t)b * L + l) * D + q * 16;
            float4 x0 = *(const float4*)&ap[0];
            float4 x1 = *(const float4*)&ap[4];
            float4 x2 = *(const float4*)&ap[8];
            float4 x3 = *(const float4*)&ap[12];
            const float* vp = &vL[q * 16];
            float dot = x0.x * vp[0] + x0.y * vp[1] + x0.z * vp[2] + x0.w * vp[3]
                      + x1.x * vp[4] + x1.y * vp[5] + x1.z * vp[6] + x1.w * vp[7]
                      + x2.x * vp[8] + x2.y * vp[9] + x2.z * vp[10] + x2.w * vp[11]
                      + x3.x * vp[12] + x3.y * vp[13] + x3.z * vp[14] + x3.w * vp[15];
            dot += __shfl_xor(dot, 1);
            dot += __shfl_xor(dot, 2);
            dot += __shfl_xor(dot, 4);
            union { ushort us[4]; uint2 u2; } pk;
            pk.us[0] = f2bf(x0.x); pk.us[1] = f2bf(x0.y);
            pk.us[2] = f2bf(x0.z); pk.us[3] = f2bf(x0.w);
            *(uint2*)&Ls[lr][q * 16] = pk.u2;
            pk.us[0] = f2bf(x1.x); pk.us[1] = f2bf(x1.y);
            pk.us[2] = f2bf(x1.z); pk.us[3] = f2bf(x1.w);
            *(uint2*)&Ls[lr][q * 16 + 4] = pk.u2;
            pk.us[0] = f2bf(x2.x); pk.us[1] = f2bf(x2.y);
            pk.us[2] = f2bf(x2.z); pk.us[3] = f2bf(x2.w);
            *(uint2*)&Ls[lr][q * 16 + 8] = pk.u2;
            pk.us[0] = f2bf(x3.x); pk.us[1] = f2bf(x3.y);
            pk.us[2] = f2bf(x3.z); pk.us[3] = f2bf(x3.w);
            *(uint2*)&Ls[lr][q * 16 + 12] = pk.u2;
            if (q == 0) {
                float msk = smask[(size_t)b * L + l];
                float s = (msk > -0.5f) ? (dot + c1) : -1e30f;
                eT[c * 32 + lr] = f2bf(__expf(s));
                fT[c * 32 + lr] = f2bf(__expf(NEG_SLOPE * s));
            }
        }
        __syncthreads();
        {   // transpose-out: thread (d = tid>>1, h = tid&1) covers 16 l
            const int d = tid >> 1, h = tid & 1;
            #pragma unroll
            for (int hh = 0; hh < 2; ++hh) {
                alignas(16) ushort tmp[8];
                #pragma unroll
                for (int m = 0; m < 8; ++m) tmp[m] = Ls[h * 16 + hh * 8 + m][d];
                const int ch = c * 4 + h * 2 + hh;
                *(int4*)((char*)&Ta[0][0] + d * 512 + ((ch ^ (d & 15)) << 4)) =
                    *(int4*)tmp;
            }
        }
        __syncthreads();
    }

    // ---- MFMA phase (R11-verified body)
    const int aG = ah * 128 + w * 32 + al;
    const float smv = smL[w * 32 + al];
    const float ea = __expf(smv), fa = __expf(NEG_SLOPE * smv);
    f32x16 acc[4] = {};
    float psum = 0.f;
    #pragma unroll 4
    for (int c = 0; c < 16; ++c) {
        const int lb = c * 16 + hi * 8;
        bf16x8 eb = *(const bf16x8*)&eT[lb];
        bf16x8 fb = *(const bf16x8*)&fT[lb];
        bf16x8 pf;
        #pragma unroll
        for (int jj = 0; jj < 8; ++jj) {
            float p_ = fmaxf(ea * bf2f((ushort)eb[jj]), fa * bf2f((ushort)fb[jj]));
            psum += p_;
            pf[jj] = (short)f2bf(p_);
        }
        const int ch = c * 2 + hi;
        #pragma unroll
        for (int dt = 0; dt < 4; ++dt) {
            const int row = dt * 32 + al;
            bf16x8 bf = *(const bf16x8*)((const char*)&Ta[0][0] + row * 512
                                         + ((ch ^ (row & 15)) << 4));
            acc[dt] = __builtin_amdgcn_mfma_f32_32x32x16_bf16(pf, bf, acc[dt], 0, 0, 0);
        }
    }

    psum += __shfl_xor(psum, 32);
    if (hi == 0) psumP[((size_t)b * 4 + lq) * A + aG] = psum;

    const size_t base0 = (((size_t)(b * 4 + lq) * 2 + ah) * 4 + w);
    #pragma unroll
    for (int dt = 0; dt < 4; ++dt) {
        #pragma unroll
        for (int rq = 0; rq < 4; ++rq) {
            union { ushort us[4]; uint2 u2; } pk;
            pk.us[0] = f2bf(acc[dt][rq * 4 + 0]);
            pk.us[1] = f2bf(acc[dt][rq * 4 + 1]);
            pk.us[2] = f2bf(acc[dt][rq * 4 + 2]);
            pk.us[3] = f2bf(acc[dt][rq * 4 + 3]);
            PP[((((base0 * 4 + dt) * 4 + rq) * 2 + hi) * 32) + al] = pk.u2;
        }
    }
}

// ---------------------------------------------------------------------------
// K3 "reduce" (R11-verified): 512 blocks (b, ah, at). Sum 4 lq partials ->
// TT bf16 (chunk-XOR) -> ctx = T.W MFMA + scale + LayerNorm -> out.
// ---------------------------------------------------------------------------
__global__ __launch_bounds__(256) void reduce_kernel(
    const uint2* __restrict__ PP, const float* __restrict__ psumP,
    const float* __restrict__ amask, const ushort* __restrict__ WB,
    const float* __restrict__ bnb,
    const float* __restrict__ gamma, const float* __restrict__ beta,
    float* __restrict__ out) {
    __shared__ __align__(16) ushort TT[32 * 128];
    __shared__ float gbL[256];
    __shared__ float lnP[4][2][16][2];

    const int bid = blockIdx.x;
    const int x = bid & 7, j = bid >> 3;
    const int b = x + 8 * (j & 7);
    const int rest = j >> 3;
    const int ah = rest >> 2, at = rest & 3;
    const int tid = threadIdx.x;
    const int w = tid >> 6, lane = tid & 63;
    const int la = lane & 15, kg = lane >> 4;
    const int xo = la & 7;
    const int aG0 = ah * 128 + at * 32;

    if (tid < 32)      ((float4*)gbL)[tid] = ((const float4*)gamma)[tid];
    else if (tid < 64) ((float4*)gbL)[tid] = ((const float4*)beta)[tid - 32];

    {
        const int rq = tid >> 6, hi2 = (tid >> 5) & 1, al2 = tid & 31;
        float s4[4][4];
        #pragma unroll
        for (int dt = 0; dt < 4; ++dt)
            #pragma unroll
            for (int e = 0; e < 4; ++e) s4[dt][e] = 0.f;
        #pragma unroll
        for (int lq = 0; lq < 4; ++lq) {
            const size_t bb = (((size_t)(b * 4 + lq) * 2 + ah) * 4 + at);
            #pragma unroll
            for (int dt = 0; dt < 4; ++dt) {
                uint2 v = PP[((((bb * 4 + dt) * 4 + rq) * 2 + hi2) * 32) + al2];
                s4[dt][0] += bf2f((ushort)(v.x & 0xffff));
                s4[dt][1] += bf2f((ushort)(v.x >> 16));
                s4[dt][2] += bf2f((ushort)(v.y & 0xffff));
                s4[dt][3] += bf2f((ushort)(v.y >> 16));
            }
        }
        #pragma unroll
        for (int dt = 0; dt < 4; ++dt) {
            const int d = dt * 32 + al2;
            const int cc = d >> 3;
            #pragma unroll
            for (int e = 0; e < 4; ++e) {
                const int arow = e + 8 * rq + 4 * hi2;
                *(ushort*)((char*)TT + arow * 256 + ((cc ^ (arow & 7)) << 4)
                           + (d & 7) * 2) = f2bf(s4[dt][e]);
            }
        }
    }

    bf16x8 wb0[4], wb1[4];
    {
        const ushort* wr0 = WB + (size_t)((2 * w) * 16 + la) * D + kg * 8;
        const ushort* wr1 = WB + (size_t)((2 * w + 1) * 16 + la) * D + kg * 8;
        #pragma unroll
        for (int ks = 0; ks < 4; ++ks) {
            wb0[ks] = *(const bf16x8*)&wr0[ks * 32];
            wb1[ks] = *(const bf16x8*)&wr1[ks * 32];
        }
    }
    float4 bias0 = *(const float4*)&bnb[w * 32 + kg * 4];
    float4 bias1 = *(const float4*)&bnb[w * 32 + 16 + kg * 4];
    const float amA = amask[(size_t)b * A + aG0 + la];
    const float amB = amask[(size_t)b * A + aG0 + 16 + la];
    float psA = 0.f, psB = 0.f;
    #pragma unroll
    for (int lq = 0; lq < 4; ++lq) {
        psA += psumP[((size_t)b * 4 + lq) * A + aG0 + la];
        psB += psumP[((size_t)b * 4 + lq) * A + aG0 + 16 + la];
    }
    __syncthreads();

    const char* TTc = (const char*)TT;
#define LDT(ROW_, KS_) (*(const bf16x8*)(TTc + (ROW_) * 256 + \
                         ((((KS_) * 4 + kg) ^ xo) << 4)))
    f32x4 cA0 = {}, cA1 = {}, cB0 = {}, cB1 = {};
    #pragma unroll
    for (int ks = 0; ks < 4; ++ks) {
        bf16x8 tA = LDT(la, ks);
        bf16x8 tB = LDT(la + 16, ks);
        cA0 = __builtin_amdgcn_mfma_f32_16x16x32_bf16(wb0[ks], tA, cA0, 0, 0, 0);
        cA1 = __builtin_amdgcn_mfma_f32_16x16x32_bf16(wb1[ks], tA, cA1, 0, 0, 0);
        cB0 = __builtin_amdgcn_mfma_f32_16x16x32_bf16(wb0[ks], tB, cB0, 0, 0, 0);
        cB1 = __builtin_amdgcn_mfma_f32_16x16x32_bf16(wb1[ks], tB, cB1, 0, 0, 0);
    }
#undef LDT

    const float scA = amA / psA, scB = amB / psB;
    float xA[8], xB[8];
    float s1A = 0.f, s2A = 0.f, s1B = 0.f, s2B = 0.f;
    const float* bp0 = (const float*)&bias0;
    const float* bp1 = (const float*)&bias1;
    #pragma unroll
    for (int r = 0; r < 4; ++r) {
        xA[r]     = cA0[r] * scA + amA * bp0[r];
        xA[4 + r] = cA1[r] * scA + amA * bp1[r];
        xB[r]     = cB0[r] * scB + amB * bp0[r];
        xB[4 + r] = cB1[r] * scB + amB * bp1[r];
        s1A += xA[r] + xA[4 + r]; s2A += xA[r] * xA[r] + xA[4 + r] * xA[4 + r];
        s1B += xB[r] + xB[4 + r]; s2B += xB[r] * xB[r] + xB[4 + r] * xB[4 + r];
    }
    s1A += __shfl_xor(s1A, 16); s1A += __shfl_xor(s1A, 32);
    s2A += __shfl_xor(s2A, 16); s2A += __shfl_xor(s2A, 32);
    s1B += __shfl_xor(s1B, 16); s1B += __shfl_xor(s1B, 32);
    s2B += __shfl_xor(s2B, 16); s2B += __shfl_xor(s2B, 32);
    if (lane < 16) {
        lnP[w][0][la][0] = s1A; lnP[w][0][la][1] = s2A;
        lnP[w][1][la][0] = s1B; lnP[w][1][la][1] = s2B;
    }
    __syncthreads();
    const float S1A = lnP[0][0][la][0] + lnP[1][0][la][0] + lnP[2][0][la][0] + lnP[3][0][la][0];
    const float S2A = lnP[0][0][la][1] + lnP[1][0][la][1] + lnP[2][0][la][1] + lnP[3][0][la][1];
    const float S1B = lnP[0][1][la][0] + lnP[1][1][la][0] + lnP[2][1][la][0] + lnP[3][1][la][0];
    const float S2B = lnP[0][1][la][1] + lnP[1][1][la][1] + lnP[2][1][la][1] + lnP[3][1][la][1];
    const float muA = S1A * (1.f / 128.f);
    const float rsA = rsqrtf(S2A * (1.f / 128.f) - muA * muA + LN_EPS);
    const float muB = S1B * (1.f / 128.f);
    const float rsB = rsqrtf(S2B * (1.f / 128.f) - muB * muB + LN_EPS);
    const size_t oA = ((size_t)b * A + aG0 + la) * D;
    const size_t oB = ((size_t)b * A + aG0 + 16 + la) * D;
    #pragma unroll
    for (int t = 0; t < 2; ++t) {
        const int e0 = w * 32 + t * 16 + kg * 4;
        float4 g4 = *(float4*)&gbL[e0];
        float4 b4 = *(float4*)&gbL[128 + e0];
        float4 ovA, ovB;
        const float* xpA = &xA[t * 4];
        const float* xpB = &xB[t * 4];
        ((float*)&ovA)[0] = (xpA[0] - muA) * rsA * g4.x + b4.x;
        ((float*)&ovA)[1] = (xpA[1] - muA) * rsA * g4.y + b4.y;
        ((float*)&ovA)[2] = (xpA[2] - muA) * rsA * g4.z + b4.z;
        ((float*)&ovA)[3] = (xpA[3] - muA) * rsA * g4.w + b4.w;
        ((float*)&ovB)[0] = (xpB[0] - muB) * rsB * g4.x + b4.x;
        ((float*)&ovB)[1] = (xpB[1] - muB) * rsB * g4.y + b4.y;
        ((float*)&ovB)[2] = (xpB[2] - muB) * rsB * g4.z + b4.z;
        ((float*)&ovB)[3] = (xpB[3] - muB) * rsB * g4.w + b4.w;
        *(float4*)&out[oA + e0] = ovA;
        *(float4*)&out[oB + e0] = ovB;
    }
}

// ---------------------------------------------------------------------------
extern "C" void kernel_launch(void* const* d_in, const int* in_sizes, int n_in,
                              void* d_out, int out_size, void* d_ws, size_t ws_size,
                              hipStream_t stream) {
    const float* molf  = (const float*)d_in[0];
    const float* atomf = (const float*)d_in[1];
    const float* amask = (const float*)d_in[2];
    const float* smask = (const float*)d_in[3];
    const float* W_mol = (const float*)d_in[4];
    const float* b_mol = (const float*)d_in[5];
    const float* W_nb  = (const float*)d_in[6];
    const float* b_nb  = (const float*)d_in[7];
    const float* w_am  = (const float*)d_in[8];
    const float* w_aa  = (const float*)d_in[9];
    const float* b_al  = (const float*)d_in[10];
    const float* gamma = (const float*)d_in[11];
    const float* beta  = (const float*)d_in[12];
    float* out = (float*)d_out;

    // ws: PP uint2 [B*4*A*D/4] | psumP [B*4*A] | u,v [D] | c0,c1 | WB bf16
    uint2* PP     = (uint2*)d_ws;
    float* psumP  = (float*)(PP + (size_t)B * 4 * A * D / 4);
    float* u_ws   = psumP + (size_t)B * 4 * A;
    float* v_ws   = u_ws + D;
    float* c0_ws  = v_ws + D;
    float* c1_ws  = c0_ws + 1;
    ushort* WB    = (ushort*)(c1_ws + 1);

    prep_kernel<<<128, 128, 0, stream>>>(W_mol, b_mol, w_am, b_al, W_nb, b_nb,
                                         w_aa, u_ws, v_ws, c0_ws, c1_ws, WB);
    pv_kernel<<<512, 256, 0, stream>>>(molf, atomf, smask, u_ws, v_ws,
                                       c0_ws, c1_ws, PP, psumP);
    reduce_kernel<<<512, 256, 0, stream>>>(PP, psumP, amask, WB, b_nb,
                                           gamma, beta, out);
}